// Round 6
// baseline (870.280 us; speedup 1.0000x reference)
//
#include <hip/hip_runtime.h>
#include <hip/hip_bf16.h>

#define NN 4096
#define EE 2048
#define RR 4
#define FF 128
#define HDD 256

typedef __attribute__((ext_vector_type(4))) float floatx4;
typedef __attribute__((ext_vector_type(8))) __bf16 bf16x8;

#define AS1 __attribute__((address_space(1)))
#define AS3 __attribute__((address_space(3)))

__device__ __forceinline__ void async16(const void* g, void* l) {
  __builtin_amdgcn_global_load_lds((const AS1 void*)(unsigned long long)(g),
                                   (AS3 void*)(unsigned int)(unsigned long long)(l),
                                   16, 0, 0);
}

__device__ inline unsigned short f2b(float x) {
  unsigned int u = __float_as_uint(x);
  unsigned int r = u + 0x7fffu + ((u >> 16) & 1u);
  return (unsigned short)(r >> 16);
}

__device__ inline float rel_w(const float* rel, int r) {
  float m = fmaxf(fmaxf(rel[0], rel[1]), fmaxf(rel[2], rel[3]));
  float s = 0.f;
#pragma unroll
  for (int i = 0; i < RR; i++) s += expf(rel[i] - m);
  return expf(rel[r] - m) / s;
}

// ==== prep1: fused {dvmask | wprep | zero(de,csbuf)} by block range ====
__global__ void k_prep1(const float* __restrict__ H, const float* __restrict__ rel,
                        const float* __restrict__ W1, const float* __restrict__ W2,
                        const float* __restrict__ W3, const float* __restrict__ imp,
                        float* __restrict__ dvs, unsigned long long* __restrict__ mask,
                        unsigned short* __restrict__ W1catT, unsigned short* __restrict__ W2T,
                        unsigned short* __restrict__ W3T, float* __restrict__ de,
                        float* __restrict__ csbuf) {
  int b = blockIdx.x;
  if (b < 4096) {
    int wave = (b << 2) | (threadIdx.x >> 6);  // = r*NN + n
    int lane = threadIdx.x & 63;
    int r = wave >> 12;
    const float* row = H + (size_t)wave * EE;
    unsigned long long* mrow = mask + (size_t)wave * (EE / 64);
    float s = 0.f;
    for (int j = 0; j < EE / 64; j++) {
      float h = row[j * 64 + lane];
      s += h;
      unsigned long long m = __ballot(h != 0.0f);
      if (lane == 0) mrow[j] = m;
    }
    for (int off = 32; off; off >>= 1) s += __shfl_down(s, off);
    if (lane == 0) {
      float rwr = rel_w(rel, r);
      dvs[wave] = rwr * rsqrtf(rwr * s + 1e-8f);
    }
  } else if (b < 4096 + 2048) {
    int idx = (b - 4096) * 256 + threadIdx.x;
    if (idx < RR * FF * HDD) {
      int o = idx % HDD, f = (idx / HDD) % FF, r = idx / (HDD * FF);
      float sg = 1.0f / (1.0f + expf(-imp[r]));
      W1catT[(size_t)o * (RR * FF) + r * FF + f] = f2b(sg * W1[((size_t)r * FF + f) * HDD + o]);
    } else if (idx < RR * FF * HDD + RR * HDD * HDD) {
      int j = idx - RR * FF * HDD;
      int c = j % HDD, o = (j / HDD) % HDD, r = j / (HDD * HDD);
      float sg = 1.0f / (1.0f + expf(-imp[RR + r]));
      W2T[j] = f2b(sg * W2[((size_t)r * HDD + c) * HDD + o]);
    } else {
      int j = idx - RR * FF * HDD - RR * HDD * HDD;
      int c = j % HDD, o = (j / HDD) % FF, r = j / (HDD * FF);
      float sg = 1.0f / (1.0f + expf(-imp[2 * RR + r]));
      W3T[j] = f2b(sg * W3[((size_t)r * HDD + c) * FF + o]);
    }
  } else {
    int i = (b - 6144) * 256 + threadIdx.x;  // 48 blocks -> 12288 slots
    if (i < RR * EE) de[i] = 0.f;
    else if (i < RR * EE + 8 * 512) csbuf[i - RR * EE] = 0.f;
  }
}

// ==== prep2: fused {maskT (bit-transpose mask1->mask2 + de counts) | Xdv build} ====
// mask2[r][e][v]: bit l of word v <-> n = v*64+l.  Xdv[r][n][f] = bf16(dv[r,n]*X[n,f])
__global__ void k_prep2(const unsigned long long* __restrict__ m1, unsigned long long* __restrict__ m2,
                        float* __restrict__ de, const float* __restrict__ X,
                        const float* __restrict__ dvs, unsigned short* __restrict__ Xdv) {
  __shared__ unsigned long long w[64 * 33];
  int t = threadIdx.x;
  if (blockIdx.x < 256) {
    int r = blockIdx.x >> 6;
    int n0 = (blockIdx.x & 63) << 6;
    const unsigned long long* src = m1 + ((size_t)r * NN + n0) * 32;
#pragma unroll
    for (int i = 0; i < 8; i++) {
      int idx = t + i * 256;
      int n = idx >> 5, W = idx & 31;
      w[n * 33 + W] = src[idx];
    }
    __syncthreads();
    int wid = t >> 6, lane = t & 63;
    int v = n0 >> 6;
#pragma unroll
    for (int Wi = 0; Wi < 8; Wi++) {
      int W = wid * 8 + Wi;
      unsigned long long myw = w[lane * 33 + W];
      unsigned long long out = 0;
      for (int b = 0; b < 64; b++) {
        unsigned long long mm = __ballot(((myw >> b) & 1ULL) != 0);
        if (lane == b) out = mm;
      }
      m2[((size_t)r * EE + W * 64 + lane) * 64 + v] = out;
      atomicAdd(&de[r * EE + W * 64 + lane], (float)__popcll(out));
    }
  } else {
    int g = (blockIdx.x - 256) * 256 + t;        // 0..262143
    int f8 = g & 15, n = (g >> 4) & (NN - 1), r = g >> 16;
    const float* xp = X + (size_t)n * FF + (f8 << 3);
    float4 v0 = *(const float4*)xp;
    float4 v1 = *(const float4*)(xp + 4);
    float d = dvs[(r << 12) + n];
    ushort4 o0, o1;
    o0.x = f2b(v0.x * d); o0.y = f2b(v0.y * d); o0.z = f2b(v0.z * d); o0.w = f2b(v0.w * d);
    o1.x = f2b(v1.x * d); o1.y = f2b(v1.y * d); o1.z = f2b(v1.z * d); o1.w = f2b(v1.w * d);
    unsigned short* dp = Xdv + ((size_t)r * NN + n) * FF + (f8 << 3);
    *(ushort4*)dp = o0;
    *(ushort4*)(dp + 4) = o1;
  }
}

// ---------------- dense MFMA GEMM, 128x128 tile, BK=64, single-barrier dbuf (R4-proven) ----------------
// C[row][col] = sum_k A[zr][m0+row][k] * BT[zr][n0+col][k]; optional f32 row-scale rscale[zr*rs_rs+row].
__global__ __launch_bounds__(256) void k_gemm3(
    const unsigned short* __restrict__ A, const unsigned short* __restrict__ BT,
    int K, int lda, int ldb, long a_rs, long b_rs,
    unsigned short* __restrict__ P, long c_rs, int ldc,
    const float* __restrict__ rscale, long rs_rs) {
  __shared__ unsigned short Al[2][128 * 64];
  __shared__ unsigned short Bl[2][128 * 64];
  int tid = threadIdx.x, wid = tid >> 6, lane = tid & 63;
  int m0 = blockIdx.x << 7, n0 = blockIdx.y << 7;
  int zr = blockIdx.z;
  int r8 = lane >> 3, c8 = lane & 7;
  int swz = ((c8 ^ r8) << 3);
  const unsigned short* Ab = A + (size_t)zr * a_rs + (size_t)m0 * lda;
  const unsigned short* Bb = BT + (size_t)zr * b_rs + (size_t)n0 * ldb;
  auto stage = [&](int pb, int k0) {
#pragma unroll
    for (int t = 0; t < 4; t++) {
      int rbase = (wid << 5) + (t << 3);
      int row = rbase + r8;
      async16(Ab + (size_t)row * lda + k0 + swz, &Al[pb][rbase * 64 + lane * 8]);
      async16(Bb + (size_t)row * ldb + k0 + swz, &Bl[pb][rbase * 64 + lane * 8]);
    }
  };
  int wm = (wid >> 1) << 6, wn = (wid & 1) << 6;
  int fm = lane & 15, quad = lane >> 4;
  int f7 = fm & 7;
  floatx4 acc[4][4];
#pragma unroll
  for (int i = 0; i < 4; i++)
#pragma unroll
    for (int j = 0; j < 4; j++) acc[i][j] = (floatx4){0.f, 0.f, 0.f, 0.f};
  auto compute = [&](int pb) {
#pragma unroll
    for (int ks = 0; ks < 2; ks++) {
      int kg = (ks << 2) | quad;
      int ko = ((kg ^ f7) << 3);
      bf16x8 a[4], b[4];
#pragma unroll
      for (int i = 0; i < 4; i++) {
        a[i] = *(const bf16x8*)&Al[pb][(wm + i * 16 + fm) * 64 + ko];
        b[i] = *(const bf16x8*)&Bl[pb][(wn + i * 16 + fm) * 64 + ko];
      }
#pragma unroll
      for (int i = 0; i < 4; i++)
#pragma unroll
        for (int j = 0; j < 4; j++)
          acc[i][j] = __builtin_amdgcn_mfma_f32_16x16x32_bf16(a[i], b[j], acc[i][j], 0, 0, 0);
    }
  };
  stage(0, 0);
  __syncthreads();
  for (int k0 = 0; k0 < K; k0 += 128) {   // all callers have K % 128 == 0
    if (k0 + 64 < K) stage(1, k0 + 64);
    compute(0);
    __syncthreads();
    if (k0 + 128 < K) stage(0, k0 + 128);
    compute(1);
    __syncthreads();
  }
  unsigned short* Cb = P + (size_t)zr * c_rs;
#pragma unroll
  for (int mi = 0; mi < 4; mi++)
#pragma unroll
    for (int v = 0; v < 4; v++) {
      int row = m0 + wm + mi * 16 + quad * 4 + v;
      float rs = rscale ? rscale[(size_t)zr * rs_rs + row] : 1.0f;
#pragma unroll
      for (int ni = 0; ni < 4; ni++) {
        int col = n0 + wn + ni * 16 + fm;
        Cb[(size_t)row * ldc + col] = f2b(acc[mi][ni][v] * rs);
      }
    }
}

// ---------------- sparse gather-SpMM, B2 side: out[r][e][C] = de2[r,e] * sum_{n in B2row} T[r][n][C] ----
// one wave per (r,e); lanes = columns; bitmask row scanned on the scalar unit via readlane;
// 1-ahead software prefetch keeps 2 loads in flight per wave (8 waves/SIMD for TLP).
template <int C>
__global__ __launch_bounds__(256) void k_b2s(
    const unsigned long long* __restrict__ mask2, const unsigned short* __restrict__ T,
    const float* __restrict__ de, const float* __restrict__ rel,
    unsigned short* __restrict__ out, float* __restrict__ csz) {
  if (blockIdx.x == 0) {
#pragma unroll
    for (int i = 0; i < 16; i++) csz[i * 256 + threadIdx.x] = 0.f;
  }
  int wv = (blockIdx.x << 2) | (threadIdx.x >> 6);   // r*EE + e
  int lane = threadIdx.x & 63;
  int r = wv >> 11, e = wv & (EE - 1);
  unsigned long long w = mask2[(size_t)wv * 64 + lane];
  unsigned int wlo = (unsigned int)w, whi = (unsigned int)(w >> 32);
  const unsigned short* Tr = T + (size_t)r * NN * C;
  float a0 = 0.f, a1 = 0.f, a2 = 0.f, a3 = 0.f;
  int v = 0;
  unsigned long long bits = 0;
  while (v < 64 && bits == 0) {
    unsigned int lo = (unsigned int)__builtin_amdgcn_readlane((int)wlo, v);
    unsigned int hi = (unsigned int)__builtin_amdgcn_readlane((int)whi, v);
    bits = ((unsigned long long)hi << 32) | lo;
    v++;
  }
  bool have = bits != 0;
  unsigned int u0 = 0, u1 = 0;
  if (have) {
    int b = __builtin_ctzll(bits);
    bits &= bits - 1;
    const unsigned short* rp = Tr + (size_t)(((v - 1) << 6) + b) * C;
    if (C == 256) { uint2 uu = *(const uint2*)(rp + (lane << 2)); u0 = uu.x; u1 = uu.y; }
    else u0 = *(const unsigned int*)(rp + (lane << 1));
  }
  while (have) {
    while (v < 64 && bits == 0) {
      unsigned int lo = (unsigned int)__builtin_amdgcn_readlane((int)wlo, v);
      unsigned int hi = (unsigned int)__builtin_amdgcn_readlane((int)whi, v);
      bits = ((unsigned long long)hi << 32) | lo;
      v++;
    }
    bool haven = bits != 0;
    unsigned int n0 = 0, n1 = 0;
    if (haven) {
      int b = __builtin_ctzll(bits);
      bits &= bits - 1;
      const unsigned short* rp = Tr + (size_t)(((v - 1) << 6) + b) * C;
      if (C == 256) { uint2 uu = *(const uint2*)(rp + (lane << 2)); n0 = uu.x; n1 = uu.y; }
      else n0 = *(const unsigned int*)(rp + (lane << 1));
    }
    a0 += __uint_as_float(u0 << 16);
    a1 += __uint_as_float(u0 & 0xffff0000u);
    if (C == 256) {
      a2 += __uint_as_float(u1 << 16);
      a3 += __uint_as_float(u1 & 0xffff0000u);
    }
    u0 = n0; u1 = n1; have = haven;
  }
  float rwr = rel_w(rel, r);
  float s = 1.0f / (rwr * de[(r << 11) + e] + 1e-8f);
  unsigned short* op = out + (size_t)wv * C;
  if (C == 256) {
    ushort4 o;
    o.x = f2b(a0 * s); o.y = f2b(a1 * s); o.z = f2b(a2 * s); o.w = f2b(a3 * s);
    *(ushort4*)(op + (lane << 2)) = o;
  } else {
    ushort2 o;
    o.x = f2b(a0 * s); o.y = f2b(a1 * s);
    *(ushort2*)(op + (lane << 1)) = o;
  }
}

// ---------------- sparse gather-SpMM, B1 side, C=256: convout[n][c] = sum_r dv[r,n]*sum_{e in B1row} T[r][e][c]
// + fused BN column stats into 8-replica csbuf.  4 waves/block: 2 n x 2 r-halves (8192 waves total).
__global__ __launch_bounds__(256) void k_b1s256(
    const unsigned long long* __restrict__ mask1, const unsigned short* __restrict__ T,
    const float* __restrict__ dvs, float* __restrict__ out, float* __restrict__ csbuf) {
  __shared__ float sm[4][256];
  int wid = threadIdx.x >> 6, lane = threadIdx.x & 63;
  int n = (blockIdx.x << 1) | (wid >> 1);
  int rh = wid & 1;
  float y0 = 0.f, y1 = 0.f, y2 = 0.f, y3 = 0.f;
#pragma unroll
  for (int rr = 0; rr < 2; rr++) {
    int r = (rh << 1) | rr;
    unsigned long long w = mask1[((size_t)(r << 12) + n) * 32 + (lane & 31)];
    unsigned int wlo = (unsigned int)w, whi = (unsigned int)(w >> 32);
    const unsigned short* Tr = T + (size_t)r * EE * 256;
    float a0 = 0.f, a1 = 0.f, a2 = 0.f, a3 = 0.f;
    int v = 0;
    unsigned long long bits = 0;
    while (v < 32 && bits == 0) {
      unsigned int lo = (unsigned int)__builtin_amdgcn_readlane((int)wlo, v);
      unsigned int hi = (unsigned int)__builtin_amdgcn_readlane((int)whi, v);
      bits = ((unsigned long long)hi << 32) | lo;
      v++;
    }
    bool have = bits != 0;
    unsigned int u0 = 0, u1 = 0;
    if (have) {
      int b = __builtin_ctzll(bits);
      bits &= bits - 1;
      const unsigned short* rp = Tr + (size_t)(((v - 1) << 6) + b) * 256;
      uint2 uu = *(const uint2*)(rp + (lane << 2));
      u0 = uu.x; u1 = uu.y;
    }
    while (have) {
      while (v < 32 && bits == 0) {
        unsigned int lo = (unsigned int)__builtin_amdgcn_readlane((int)wlo, v);
        unsigned int hi = (unsigned int)__builtin_amdgcn_readlane((int)whi, v);
        bits = ((unsigned long long)hi << 32) | lo;
        v++;
      }
      bool haven = bits != 0;
      unsigned int p0 = 0, p1 = 0;
      if (haven) {
        int b = __builtin_ctzll(bits);
        bits &= bits - 1;
        const unsigned short* rp = Tr + (size_t)(((v - 1) << 6) + b) * 256;
        uint2 uu = *(const uint2*)(rp + (lane << 2));
        p0 = uu.x; p1 = uu.y;
      }
      a0 += __uint_as_float(u0 << 16);
      a1 += __uint_as_float(u0 & 0xffff0000u);
      a2 += __uint_as_float(u1 << 16);
      a3 += __uint_as_float(u1 & 0xffff0000u);
      u0 = p0; u1 = p1; have = haven;
    }
    float dv = dvs[(r << 12) + n];
    y0 += dv * a0; y1 += dv * a1; y2 += dv * a2; y3 += dv * a3;
  }
  float4 yv = {y0, y1, y2, y3};
  *(float4*)&sm[wid][lane << 2] = yv;
  __syncthreads();
  int c = threadIdx.x;
  float ya = sm[0][c] + sm[1][c];
  float yb = sm[2][c] + sm[3][c];
  int n0 = blockIdx.x << 1;
  out[(size_t)n0 * HDD + c] = ya;
  out[(size_t)(n0 + 1) * HDD + c] = yb;
  float* csb = csbuf + ((blockIdx.x & 7) << 9);
  atomicAdd(&csb[c], ya + yb);
  atomicAdd(&csb[c + 256], ya * ya + yb * yb);
}

// ---------------- sparse gather-SpMM, B1 side, C=128, FINAL: d_out = X + b3 + sum_r dv*gather(T) ----
__global__ __launch_bounds__(256) void k_b1s128o(
    const unsigned long long* __restrict__ mask1, const unsigned short* __restrict__ T,
    const float* __restrict__ dvs, const float* __restrict__ X, const float* __restrict__ b3,
    float* __restrict__ out) {
  __shared__ float sm[4][128];
  int wid = threadIdx.x >> 6, lane = threadIdx.x & 63;
  int n = (blockIdx.x << 1) | (wid >> 1);
  int rh = wid & 1;
  float y0 = 0.f, y1 = 0.f;
#pragma unroll
  for (int rr = 0; rr < 2; rr++) {
    int r = (rh << 1) | rr;
    unsigned long long w = mask1[((size_t)(r << 12) + n) * 32 + (lane & 31)];
    unsigned int wlo = (unsigned int)w, whi = (unsigned int)(w >> 32);
    const unsigned short* Tr = T + (size_t)r * EE * 128;
    float a0 = 0.f, a1 = 0.f;
    int v = 0;
    unsigned long long bits = 0;
    while (v < 32 && bits == 0) {
      unsigned int lo = (unsigned int)__builtin_amdgcn_readlane((int)wlo, v);
      unsigned int hi = (unsigned int)__builtin_amdgcn_readlane((int)whi, v);
      bits = ((unsigned long long)hi << 32) | lo;
      v++;
    }
    bool have = bits != 0;
    unsigned int u0 = 0;
    if (have) {
      int b = __builtin_ctzll(bits);
      bits &= bits - 1;
      const unsigned short* rp = Tr + (size_t)(((v - 1) << 6) + b) * 128;
      u0 = *(const unsigned int*)(rp + (lane << 1));
    }
    while (have) {
      while (v < 32 && bits == 0) {
        unsigned int lo = (unsigned int)__builtin_amdgcn_readlane((int)wlo, v);
        unsigned int hi = (unsigned int)__builtin_amdgcn_readlane((int)whi, v);
        bits = ((unsigned long long)hi << 32) | lo;
        v++;
      }
      bool haven = bits != 0;
      unsigned int p0 = 0;
      if (haven) {
        int b = __builtin_ctzll(bits);
        bits &= bits - 1;
        const unsigned short* rp = Tr + (size_t)(((v - 1) << 6) + b) * 128;
        p0 = *(const unsigned int*)(rp + (lane << 1));
      }
      a0 += __uint_as_float(u0 << 16);
      a1 += __uint_as_float(u0 & 0xffff0000u);
      u0 = p0; have = haven;
    }
    float dv = dvs[(r << 12) + n];
    y0 += dv * a0; y1 += dv * a1;
  }
  float2 yv = {y0, y1};
  *(float2*)&sm[wid][lane << 1] = yv;
  __syncthreads();
  int t = threadIdx.x;
  int c = t & 127, nl = t >> 7;
  int nn = (blockIdx.x << 1) + nl;
  float y = sm[nl * 2][c] + sm[nl * 2 + 1][c];
  out[(size_t)nn * FF + c] = X[(size_t)nn * FF + c] + b3[c] + y;
}

// ---- BN (batch stats from 8-replica csbuf) -> LN -> ELU -> bf16 [NN][HDD] ----
__global__ void k_bnlnelu(const float* __restrict__ x, const float* __restrict__ csbuf,
                          const float* __restrict__ bg, const float* __restrict__ bb,
                          const float* __restrict__ lg, const float* __restrict__ lb,
                          unsigned short* __restrict__ out) {
  int wid = threadIdx.x >> 6, lane = threadIdx.x & 63;
  int n = blockIdx.x * 4 + wid;
  float y[4];
  float m = 0.f;
#pragma unroll
  for (int j = 0; j < 4; j++) {
    int c = lane + 64 * j;
    float s0 = 0.f, s1 = 0.f;
#pragma unroll
    for (int k = 0; k < 8; k++) {
      s0 += csbuf[k * 512 + c];
      s1 += csbuf[k * 512 + 256 + c];
    }
    float mu = s0 * (1.0f / NN);
    float var = s1 * (1.0f / NN) - mu * mu;
    float xv = x[(size_t)n * HDD + c];
    y[j] = (xv - mu) * rsqrtf(var + 1e-5f) * bg[c] + bb[c];
    m += y[j];
  }
  for (int off = 32; off; off >>= 1) m += __shfl_down(m, off);
  m = __shfl(m, 0) * (1.0f / HDD);
  float var = 0.f;
#pragma unroll
  for (int j = 0; j < 4; j++) { float d = y[j] - m; var += d * d; }
  for (int off = 32; off; off >>= 1) var += __shfl_down(var, off);
  var = __shfl(var, 0) * (1.0f / HDD);
  float inv = rsqrtf(var + 1e-5f);
#pragma unroll
  for (int j = 0; j < 4; j++) {
    int c = lane + 64 * j;
    float z = (y[j] - m) * inv * lg[c] + lb[c];
    z = z > 0.f ? z : expm1f(z);
    out[(size_t)n * HDD + c] = f2b(z);
  }
}

extern "C" void kernel_launch(void* const* d_in, const int* in_sizes, int n_in,
                              void* d_out, int out_size, void* d_ws, size_t ws_size,
                              hipStream_t stream) {
  const float* X   = (const float*)d_in[0];
  const float* H   = (const float*)d_in[1];
  const float* W1  = (const float*)d_in[2];
  const float* W2  = (const float*)d_in[3];
  const float* W3  = (const float*)d_in[4];
  const float* imp = (const float*)d_in[5];
  const float* b3  = (const float*)d_in[8];
  const float* bng = (const float*)d_in[9];
  const float* bnb = (const float*)d_in[10];
  const float* lng = (const float*)d_in[11];
  const float* lnb = (const float*)d_in[12];
  const float* rel = (const float*)d_in[13];
  (void)in_sizes; (void)n_in; (void)out_size; (void)ws_size;

  char* w = (char*)d_ws;
  size_t off = 0;
  auto alloc = [&](size_t bytes) -> void* {
    void* p = w + off;
    off += (bytes + 255) & ~(size_t)255;
    return p;
  };
  float* dvs   = (float*)alloc((size_t)RR * NN * 4);
  float* de    = (float*)alloc((size_t)RR * EE * 4);
  float* csbuf = (float*)alloc(8 * 512 * 4);                                   // 8 replicas of [cs|cs2]
  unsigned long long* mask1 = (unsigned long long*)alloc((size_t)RR * NN * 32 * 8);  // 4MB
  unsigned long long* mask2 = (unsigned long long*)alloc((size_t)RR * EE * 64 * 8);  // 4MB
  unsigned short* Xdv  = (unsigned short*)alloc((size_t)RR * NN * FF * 2);     // 4MB
  unsigned short* t1   = (unsigned short*)alloc((size_t)RR * EE * FF * 2);     // 2MB
  unsigned short* Z1   = (unsigned short*)alloc((size_t)RR * EE * HDD * 2);    // 4MB
  float* convout       = (float*)alloc((size_t)NN * HDD * 4);                  // 4MB
  unsigned short* Xb   = (unsigned short*)alloc((size_t)NN * HDD * 2);         // 2MB
  unsigned short* hwdv = (unsigned short*)alloc((size_t)RR * NN * HDD * 2);    // 8MB
  unsigned short* t2   = (unsigned short*)alloc((size_t)RR * EE * HDD * 2);    // 4MB
  unsigned short* ydv  = (unsigned short*)alloc((size_t)RR * NN * FF * 2);     // 4MB
  unsigned short* t3   = (unsigned short*)alloc((size_t)RR * EE * FF * 2);     // 2MB
  unsigned short* W1catT = (unsigned short*)alloc((size_t)RR * FF * HDD * 2);
  unsigned short* W2T    = (unsigned short*)alloc((size_t)RR * HDD * HDD * 2);
  unsigned short* W3T    = (unsigned short*)alloc((size_t)RR * HDD * FF * 2);

  // ---- prep ----
  k_prep1<<<4096 + 2048 + 48, 256, 0, stream>>>(H, rel, W1, W2, W3, imp,
                                                dvs, mask1, W1catT, W2T, W3T, de, csbuf);
  k_prep2<<<256 + 1024, 256, 0, stream>>>(mask1, mask2, de, X, dvs, Xdv);

  // ---- layer 1 (128 -> 256) ----
  // t1[r][e][f] = de2[r,e] * sum_n B2[r,e,n] Xdv[r][n][f]
  k_b2s<128><<<2048, 256, 0, stream>>>(mask2, Xdv, de, rel, t1, csbuf);
  // Z1[r][e][o] = sum_f t1[r][e][f] * W1catT[o][r*FF+f]   M=2048,N=256,K=128, z=r
  k_gemm3<<<dim3(EE / 128, HDD / 128, RR), 256, 0, stream>>>(
      t1, W1catT, FF, FF, RR * FF, (long)EE * FF, FF, Z1, (long)EE * HDD, HDD, nullptr, 0);
  // convout[n][o] = sum_r dv[r,n] sum_e B1[r,n,e] Z1[r][e][o]  (+ BN stats)
  k_b1s256<<<NN / 2, 256, 0, stream>>>(mask1, Z1, dvs, convout, csbuf);
  k_bnlnelu<<<NN / 4, 256, 0, stream>>>(convout, csbuf, bng, bnb, lng, lnb, Xb);

  // ---- layer 2 (256 -> 256), W2 applied first ----
  // hwdv[r][n][o] = dv[r,n] * sum_c Xb[n][c] W2T[r][o][c]   M=4096,N=256,K=256, z=r
  k_gemm3<<<dim3(NN / 128, HDD / 128, RR), 256, 0, stream>>>(
      Xb, W2T, HDD, HDD, HDD, 0, (long)HDD * HDD, hwdv, (long)NN * HDD, HDD, dvs, NN);
  // t2[r][e][o] = de2[r,e] * sum_n B2 hwdv   (also zeroes csbuf for L2 stats)
  k_b2s<256><<<2048, 256, 0, stream>>>(mask2, hwdv, de, rel, t2, csbuf);
  k_b1s256<<<NN / 2, 256, 0, stream>>>(mask1, t2, dvs, convout, csbuf);
  k_bnlnelu<<<NN / 4, 256, 0, stream>>>(convout, csbuf, bng + HDD, bnb + HDD, lng + HDD, lnb + HDD, Xb);

  // ---- layer 3 (256 -> 128), W3 applied first ----
  // ydv[r][n][f] = dv[r,n] * sum_c Xb[n][c] W3T[r][f][c]   M=4096,N=128,K=256, z=r
  k_gemm3<<<dim3(NN / 128, 1, RR), 256, 0, stream>>>(
      Xb, W3T, HDD, HDD, HDD, 0, (long)FF * HDD, ydv, (long)NN * FF, FF, dvs, NN);
  // t3[r][e][f] = de2[r,e] * sum_n B2 ydv
  k_b2s<128><<<2048, 256, 0, stream>>>(mask2, ydv, de, rel, t3, csbuf);
  // d_out = X + b3 + sum_r dv * B1-gather(t3)
  k_b1s128o<<<NN / 2, 256, 0, stream>>>(mask1, t3, dvs, X, b3, (float*)d_out);
}

// Round 7
// 565.039 us; speedup vs baseline: 1.5402x; 1.5402x over previous
//
#include <hip/hip_runtime.h>
#include <hip/hip_bf16.h>

#define NN 4096
#define EE 2048
#define RR 4
#define FF 128
#define HDD 256
#define S1 192
#define S2 320

typedef __attribute__((ext_vector_type(4))) float floatx4;
typedef __attribute__((ext_vector_type(8))) __bf16 bf16x8;
typedef __attribute__((ext_vector_type(8))) unsigned short u16x8;

#define AS1 __attribute__((address_space(1)))
#define AS3 __attribute__((address_space(3)))

__device__ __forceinline__ void async16(const void* g, void* l) {
  __builtin_amdgcn_global_load_lds((const AS1 void*)(unsigned long long)(g),
                                   (AS3 void*)(unsigned int)(unsigned long long)(l),
                                   16, 0, 0);
}

__device__ inline unsigned short f2b(float x) {
  unsigned int u = __float_as_uint(x);
  unsigned int r = u + 0x7fffu + ((u >> 16) & 1u);
  return (unsigned short)(r >> 16);
}

__device__ inline float rel_w(const float* rel, int r) {
  float m = fmaxf(fmaxf(rel[0], rel[1]), fmaxf(rel[2], rel[3]));
  float s = 0.f;
#pragma unroll
  for (int i = 0; i < RR; i++) s += expf(rel[i] - m);
  return expf(rel[r] - m) / s;
}

// ==== prep1: {H scan -> dvs, mask1, csr1 (padded e-lists) | wprep | zero cnt2} ====
__global__ void k_prep1(const float* __restrict__ H, const float* __restrict__ rel,
                        const float* __restrict__ W1, const float* __restrict__ W2,
                        const float* __restrict__ W3, const float* __restrict__ imp,
                        float* __restrict__ dvs, unsigned long long* __restrict__ mask,
                        unsigned short* __restrict__ idx1, int* __restrict__ cnt1,
                        unsigned short* __restrict__ W1catT, unsigned short* __restrict__ W2T,
                        unsigned short* __restrict__ W3T, int* __restrict__ cnt2) {
  int b = blockIdx.x;
  if (b < 4096) {
    int wave = (b << 2) | (threadIdx.x >> 6);  // = r*NN + n
    int lane = threadIdx.x & 63;
    int r = wave >> 12;
    const float* row = H + (size_t)wave * EE;
    unsigned long long* mrow = mask + (size_t)wave * 32;
    unsigned short* list = idx1 + (size_t)wave * S1;
    int tot = 0;
    for (int j = 0; j < 32; j++) {
      float h = row[j * 64 + lane];
      unsigned long long m = __ballot(h != 0.0f);
      if (lane == 0) mrow[j] = m;
      if (h != 0.0f) {
        int pos = tot + __popcll(m & ((1ull << lane) - 1ull));
        if (pos < S1) list[pos] = (unsigned short)(j * 64 + lane);
      }
      tot += __popcll(m);
    }
    int tc = tot < S1 ? tot : S1;
    int padded = (tc + 7) & ~7;
    if (padded == 0) padded = 8;
    unsigned short padE = (unsigned short)((RR - r) << 11);  // -> global e-row RR*EE (zero row)
    if (lane < padded - tc) list[tc + lane] = padE;
    if (lane == 0) {
      cnt1[wave] = tc;
      float rwr = rel_w(rel, r);
      dvs[wave] = rwr * rsqrtf(rwr * (float)tot + 1e-8f);
    }
  } else if (b < 4096 + 2048) {
    int idx = (b - 4096) * 256 + threadIdx.x;
    if (idx < RR * FF * HDD) {
      int o = idx % HDD, f = (idx / HDD) % FF, r = idx / (HDD * FF);
      float sg = 1.0f / (1.0f + expf(-imp[r]));
      W1catT[(size_t)o * (RR * FF) + r * FF + f] = f2b(sg * W1[((size_t)r * FF + f) * HDD + o]);
    } else if (idx < RR * FF * HDD + RR * HDD * HDD) {
      int j = idx - RR * FF * HDD;
      int c = j % HDD, o = (j / HDD) % HDD, r = j / (HDD * HDD);
      float sg = 1.0f / (1.0f + expf(-imp[RR + r]));
      W2T[j] = f2b(sg * W2[((size_t)r * HDD + c) * HDD + o]);
    } else {
      int j = idx - RR * FF * HDD - RR * HDD * HDD;
      int c = j % HDD, o = (j / HDD) % FF, r = j / (HDD * FF);
      float sg = 1.0f / (1.0f + expf(-imp[2 * RR + r]));
      W3T[j] = f2b(sg * W3[((size_t)r * HDD + c) * FF + o]);
    }
  } else {
    int i = (b - 6144) * 256 + threadIdx.x;
    if (i < RR * EE) cnt2[i] = 0;
  }
}

// ==== prep2: {mask1 bit-transpose -> csr2 scatter (atomic offsets) | Xdv build} ====
__global__ void k_prep2(const unsigned long long* __restrict__ m1, int* __restrict__ cnt2,
                        unsigned short* __restrict__ idx2, const float* __restrict__ X,
                        const float* __restrict__ dvs, unsigned short* __restrict__ Xdv) {
  __shared__ unsigned long long w[64 * 33];
  int t = threadIdx.x;
  if (blockIdx.x < 256) {
    int r = blockIdx.x >> 6;
    int n0 = (blockIdx.x & 63) << 6;
    const unsigned long long* src = m1 + ((size_t)(r << 12) + n0) * 32;
#pragma unroll
    for (int i = 0; i < 8; i++) {
      int idx = t + i * 256;
      int n = idx >> 5, W = idx & 31;
      w[n * 33 + W] = src[idx];
    }
    __syncthreads();
    int wid = t >> 6, lane = t & 63;
#pragma unroll
    for (int Wi = 0; Wi < 8; Wi++) {
      int W = wid * 8 + Wi;
      unsigned long long myw = w[lane * 33 + W];
      unsigned long long out = 0;
      for (int bb = 0; bb < 64; bb++) {
        unsigned long long mm = __ballot(((myw >> bb) & 1ull) != 0);
        if (lane == bb) out = mm;
      }
      if (out) {
        int e = W * 64 + lane;
        int rowid = (r << 11) + e;
        int c = __popcll(out);
        int off = atomicAdd(&cnt2[rowid], c);
        unsigned long long bb2 = out;
        while (bb2) {
          int l = __builtin_ctzll(bb2);
          bb2 &= bb2 - 1;
          if (off < S2) idx2[(size_t)rowid * S2 + off] = (unsigned short)(n0 + l);
          off++;
        }
      }
    }
  } else {
    int g = (blockIdx.x - 256) * 256 + t;        // 0..262143
    int f8 = g & 15, n = (g >> 4) & (NN - 1), r = g >> 16;
    const float* xp = X + (size_t)n * FF + (f8 << 3);
    float4 v0 = *(const float4*)xp;
    float4 v1 = *(const float4*)(xp + 4);
    float d = dvs[(r << 12) + n];
    ushort4 o0, o1;
    o0.x = f2b(v0.x * d); o0.y = f2b(v0.y * d); o0.z = f2b(v0.z * d); o0.w = f2b(v0.w * d);
    o1.x = f2b(v1.x * d); o1.y = f2b(v1.y * d); o1.z = f2b(v1.z * d); o1.w = f2b(v1.w * d);
    unsigned short* dp = Xdv + ((size_t)(r << 12) + n) * FF + (f8 << 3);
    *(ushort4*)dp = o0;
    *(ushort4*)(dp + 4) = o1;
  }
}

// ==== prep3: {pad csr2 lists | zero the 7 single pad rows} ====
__global__ void k_prep3(int* __restrict__ cnt2, unsigned short* __restrict__ idx2,
                        unsigned short* __restrict__ Xdv, unsigned short* __restrict__ hwdv,
                        unsigned short* __restrict__ ydv, unsigned short* __restrict__ t1,
                        unsigned short* __restrict__ t2, unsigned short* __restrict__ t3,
                        unsigned short* __restrict__ Z1) {
  int b = blockIdx.x, t = threadIdx.x;
  if (b < 32) {
    int row = (b << 8) + t;          // 0..8191 = r*EE + e
    int r = row >> 11;
    int cnt = cnt2[row];
    if (cnt > S2) { cnt = S2; cnt2[row] = S2; }
    int padded = (cnt + 7) & ~7;
    if (padded == 0) padded = 8;
    unsigned short pv = (unsigned short)((RR - r) << 12);  // -> global n-row RR*NN (zero row)
    for (int i = cnt; i < padded; i++) idx2[(size_t)row * S2 + i] = pv;
  } else {
    int q = b - 32;
    unsigned short* p; int C;
    switch (q) {
      case 0: p = Xdv  + (size_t)(RR * NN) * FF;  C = FF;  break;
      case 1: p = hwdv + (size_t)(RR * NN) * HDD; C = HDD; break;
      case 2: p = ydv  + (size_t)(RR * NN) * FF;  C = FF;  break;
      case 3: p = t1   + (size_t)(RR * EE) * FF;  C = FF;  break;
      case 4: p = t2   + (size_t)(RR * EE) * HDD; C = HDD; break;
      case 5: p = t3   + (size_t)(RR * EE) * FF;  C = FF;  break;
      default: p = Z1  + (size_t)(RR * EE) * HDD; C = HDD; break;
    }
    if (t < C) p[t] = 0;
  }
}

// ---------------- dense MFMA GEMM, 128x128 tile, BK=64, single-barrier dbuf (R4-proven) ----------------
__global__ __launch_bounds__(256) void k_gemm3(
    const unsigned short* __restrict__ A, const unsigned short* __restrict__ BT,
    int K, int lda, int ldb, long a_rs, long b_rs,
    unsigned short* __restrict__ P, long c_rs, int ldc,
    const float* __restrict__ rscale, long rs_rs) {
  __shared__ unsigned short Al[2][128 * 64];
  __shared__ unsigned short Bl[2][128 * 64];
  int tid = threadIdx.x, wid = tid >> 6, lane = tid & 63;
  int m0 = blockIdx.x << 7, n0 = blockIdx.y << 7;
  int zr = blockIdx.z;
  int r8 = lane >> 3, c8 = lane & 7;
  int swz = ((c8 ^ r8) << 3);
  const unsigned short* Ab = A + (size_t)zr * a_rs + (size_t)m0 * lda;
  const unsigned short* Bb = BT + (size_t)zr * b_rs + (size_t)n0 * ldb;
  auto stage = [&](int pb, int k0) {
#pragma unroll
    for (int t = 0; t < 4; t++) {
      int rbase = (wid << 5) + (t << 3);
      int row = rbase + r8;
      async16(Ab + (size_t)row * lda + k0 + swz, &Al[pb][rbase * 64 + lane * 8]);
      async16(Bb + (size_t)row * ldb + k0 + swz, &Bl[pb][rbase * 64 + lane * 8]);
    }
  };
  int wm = (wid >> 1) << 6, wn = (wid & 1) << 6;
  int fm = lane & 15, quad = lane >> 4;
  int f7 = fm & 7;
  floatx4 acc[4][4];
#pragma unroll
  for (int i = 0; i < 4; i++)
#pragma unroll
    for (int j = 0; j < 4; j++) acc[i][j] = (floatx4){0.f, 0.f, 0.f, 0.f};
  auto compute = [&](int pb) {
#pragma unroll
    for (int ks = 0; ks < 2; ks++) {
      int kg = (ks << 2) | quad;
      int ko = ((kg ^ f7) << 3);
      bf16x8 a[4], b[4];
#pragma unroll
      for (int i = 0; i < 4; i++) {
        a[i] = *(const bf16x8*)&Al[pb][(wm + i * 16 + fm) * 64 + ko];
        b[i] = *(const bf16x8*)&Bl[pb][(wn + i * 16 + fm) * 64 + ko];
      }
#pragma unroll
      for (int i = 0; i < 4; i++)
#pragma unroll
        for (int j = 0; j < 4; j++)
          acc[i][j] = __builtin_amdgcn_mfma_f32_16x16x32_bf16(a[i], b[j], acc[i][j], 0, 0, 0);
    }
  };
  stage(0, 0);
  __syncthreads();
  for (int k0 = 0; k0 < K; k0 += 128) {
    if (k0 + 64 < K) stage(1, k0 + 64);
    compute(0);
    __syncthreads();
    if (k0 + 128 < K) stage(0, k0 + 128);
    compute(1);
    __syncthreads();
  }
  unsigned short* Cb = P + (size_t)zr * c_rs;
#pragma unroll
  for (int mi = 0; mi < 4; mi++)
#pragma unroll
    for (int v = 0; v < 4; v++) {
      int row = m0 + wm + mi * 16 + quad * 4 + v;
      float rs = rscale ? rscale[(size_t)zr * rs_rs + row] : 1.0f;
#pragma unroll
      for (int ni = 0; ni < 4; ni++) {
        int col = n0 + wn + ni * 16 + fm;
        Cb[(size_t)row * ldc + col] = f2b(acc[mi][ni][v] * rs);
      }
    }
}

// ---------------- sparse gather, B2 side: out[(r,e)][C] = de2 * sum_{n in csr2 row} T[(r,n)][C] ----------------
// wave per (r,e); 8-deep batched gathers, double-buffered; pad entries hit the zeroed pad row.
template <int C>
__global__ __launch_bounds__(256) void k_b2s(
    const int* __restrict__ cnt2, const unsigned short* __restrict__ idx2,
    const unsigned short* __restrict__ T, const float* __restrict__ rel,
    unsigned short* __restrict__ out, float* __restrict__ csz) {
  if (blockIdx.x == 0) { csz[threadIdx.x] = 0.f; csz[threadIdx.x + 256] = 0.f; }
  int wid = threadIdx.x >> 6, lane = threadIdx.x & 63;
  int wv = (blockIdx.x << 2) | wid;   // r*EE + e
  int r = wv >> 11;
  int cnt = cnt2[wv];
  const unsigned short* list = idx2 + (size_t)wv * S2;
  const unsigned short* Tb = T + ((size_t)(r << 12)) * C;
  int lo = (C == 256) ? (lane << 2) : (lane << 1);
  float a0 = 0.f, a1 = 0.f, a2 = 0.f, a3 = 0.f;
  int nb = (cnt + 7) >> 3;
  uint2 u[8];
  {
    u16x8 I = *(const u16x8*)list;
#pragma unroll
    for (int k = 0; k < 8; k++) {
      const unsigned short* p = Tb + (size_t)((unsigned short)I[k]) * C + lo;
      if (C == 256) u[k] = *(const uint2*)p;
      else { u[k].x = *(const unsigned int*)p; u[k].y = 0; }
    }
  }
  for (int b = 0; b < nb; b++) {
    int bn = (b + 1 < nb) ? b + 1 : b;
    u16x8 I = *(const u16x8*)(list + (bn << 3));
    uint2 un[8];
#pragma unroll
    for (int k = 0; k < 8; k++) {
      const unsigned short* p = Tb + (size_t)((unsigned short)I[k]) * C + lo;
      if (C == 256) un[k] = *(const uint2*)p;
      else { un[k].x = *(const unsigned int*)p; un[k].y = 0; }
    }
#pragma unroll
    for (int k = 0; k < 8; k++) {
      a0 += __uint_as_float(u[k].x << 16);
      a1 += __uint_as_float(u[k].x & 0xffff0000u);
      if (C == 256) {
        a2 += __uint_as_float(u[k].y << 16);
        a3 += __uint_as_float(u[k].y & 0xffff0000u);
      }
    }
#pragma unroll
    for (int k = 0; k < 8; k++) u[k] = un[k];
  }
  float rwr = rel_w(rel, r);
  float s = 1.0f / (rwr * (float)cnt + 1e-8f);
  unsigned short* op = out + (size_t)wv * C;
  if (C == 256) {
    ushort4 o;
    o.x = f2b(a0 * s); o.y = f2b(a1 * s); o.z = f2b(a2 * s); o.w = f2b(a3 * s);
    *(ushort4*)(op + (lane << 2)) = o;
  } else {
    ushort2 o;
    o.x = f2b(a0 * s); o.y = f2b(a1 * s);
    *(ushort2*)(op + (lane << 1)) = o;
  }
}

// ---------------- sparse gather, B1 side, C=256: convout[n][c] = sum_r dv[r,n] * sum_{e in csr1 row} T[(r,e)][c]
// block per n, 4 waves = 4 r, LDS combine.
__global__ __launch_bounds__(256) void k_b1s256(
    const int* __restrict__ cnt1, const unsigned short* __restrict__ idx1,
    const unsigned short* __restrict__ T, const float* __restrict__ dvs,
    float* __restrict__ out) {
  __shared__ float sm[4][256];
  int wid = threadIdx.x >> 6, lane = threadIdx.x & 63;
  int n = blockIdx.x;
  int rn = (wid << 12) + n;
  int cnt = cnt1[rn];
  const unsigned short* list = idx1 + (size_t)rn * S1;
  const unsigned short* Tb = T + ((size_t)(wid << 11)) * 256;
  float a0 = 0.f, a1 = 0.f, a2 = 0.f, a3 = 0.f;
  int nb = (cnt + 7) >> 3;
  uint2 u[8];
  {
    u16x8 I = *(const u16x8*)list;
#pragma unroll
    for (int k = 0; k < 8; k++)
      u[k] = *(const uint2*)(Tb + (size_t)((unsigned short)I[k]) * 256 + (lane << 2));
  }
  for (int b = 0; b < nb; b++) {
    int bn = (b + 1 < nb) ? b + 1 : b;
    u16x8 I = *(const u16x8*)(list + (bn << 3));
    uint2 un[8];
#pragma unroll
    for (int k = 0; k < 8; k++)
      un[k] = *(const uint2*)(Tb + (size_t)((unsigned short)I[k]) * 256 + (lane << 2));
#pragma unroll
    for (int k = 0; k < 8; k++) {
      a0 += __uint_as_float(u[k].x << 16);
      a1 += __uint_as_float(u[k].x & 0xffff0000u);
      a2 += __uint_as_float(u[k].y << 16);
      a3 += __uint_as_float(u[k].y & 0xffff0000u);
    }
#pragma unroll
    for (int k = 0; k < 8; k++) u[k] = un[k];
  }
  float dv = dvs[rn];
  float4 yv = {dv * a0, dv * a1, dv * a2, dv * a3};
  *(float4*)&sm[wid][lane << 2] = yv;
  __syncthreads();
  int c = threadIdx.x;
  out[(size_t)n * HDD + c] = sm[0][c] + sm[1][c] + sm[2][c] + sm[3][c];
}

// ---------------- sparse gather, B1 side, C=128, FINAL: d_out = X + b3 + sum_r dv * gather ----------------
__global__ __launch_bounds__(256) void k_b1s128o(
    const int* __restrict__ cnt1, const unsigned short* __restrict__ idx1,
    const unsigned short* __restrict__ T, const float* __restrict__ dvs,
    const float* __restrict__ X, const float* __restrict__ b3, float* __restrict__ out) {
  __shared__ float sm[4][128];
  int wid = threadIdx.x >> 6, lane = threadIdx.x & 63;
  int n = blockIdx.x;
  int rn = (wid << 12) + n;
  int cnt = cnt1[rn];
  const unsigned short* list = idx1 + (size_t)rn * S1;
  const unsigned short* Tb = T + ((size_t)(wid << 11)) * 128;
  float a0 = 0.f, a1 = 0.f;
  int nb = (cnt + 7) >> 3;
  unsigned int u[8];
  {
    u16x8 I = *(const u16x8*)list;
#pragma unroll
    for (int k = 0; k < 8; k++)
      u[k] = *(const unsigned int*)(Tb + (size_t)((unsigned short)I[k]) * 128 + (lane << 1));
  }
  for (int b = 0; b < nb; b++) {
    int bn = (b + 1 < nb) ? b + 1 : b;
    u16x8 I = *(const u16x8*)(list + (bn << 3));
    unsigned int un[8];
#pragma unroll
    for (int k = 0; k < 8; k++)
      un[k] = *(const unsigned int*)(Tb + (size_t)((unsigned short)I[k]) * 128 + (lane << 1));
#pragma unroll
    for (int k = 0; k < 8; k++) {
      a0 += __uint_as_float(u[k] << 16);
      a1 += __uint_as_float(u[k] & 0xffff0000u);
    }
#pragma unroll
    for (int k = 0; k < 8; k++) u[k] = un[k];
  }
  float dv = dvs[rn];
  float2 yv = {dv * a0, dv * a1};
  *(float2*)&sm[wid][lane << 1] = yv;
  __syncthreads();
  int t = threadIdx.x;
  if (t < 128) {
    float y = sm[0][t] + sm[1][t] + sm[2][t] + sm[3][t];
    out[(size_t)n * FF + t] = X[(size_t)n * FF + t] + b3[t] + y;
  }
}

// ---- BN column stats over convout f32 [NN][HDD] -> cs/cs2 (atomic per block) ----
__global__ void k_stats(const float* __restrict__ x, float* __restrict__ cs) {
  __shared__ float sm[2][8][256];
  int cg = (threadIdx.x & 31) << 3;
  int rowt = threadIdx.x >> 5;
  int r0 = blockIdx.x * 32;
  float s[8] = {0, 0, 0, 0, 0, 0, 0, 0}, s2[8] = {0, 0, 0, 0, 0, 0, 0, 0};
  for (int j = 0; j < 4; j++) {
    const float* p = x + (size_t)(r0 + rowt * 4 + j) * HDD + cg;
    float4 v0 = *(const float4*)p;
    float4 v1 = *(const float4*)(p + 4);
    float vv[8] = {v0.x, v0.y, v0.z, v0.w, v1.x, v1.y, v1.z, v1.w};
#pragma unroll
    for (int i = 0; i < 8; i++) { s[i] += vv[i]; s2[i] += vv[i] * vv[i]; }
  }
#pragma unroll
  for (int i = 0; i < 8; i++) { sm[0][rowt][cg + i] = s[i]; sm[1][rowt][cg + i] = s2[i]; }
  __syncthreads();
  int c = threadIdx.x;
  float a0 = 0, a1 = 0;
#pragma unroll
  for (int t = 0; t < 8; t++) { a0 += sm[0][t][c]; a1 += sm[1][t][c]; }
  atomicAdd(&cs[c], a0);
  atomicAdd(&cs[c + 256], a1);
}

// ---- BN (batch stats) -> LN -> ELU -> bf16 [NN][HDD] ----
__global__ void k_bnlnelu(const float* __restrict__ x, const float* __restrict__ cs,
                          const float* __restrict__ bg, const float* __restrict__ bb,
                          const float* __restrict__ lg, const float* __restrict__ lb,
                          unsigned short* __restrict__ out) {
  int wid = threadIdx.x >> 6, lane = threadIdx.x & 63;
  int n = blockIdx.x * 4 + wid;
  float y[4];
  float m = 0.f;
#pragma unroll
  for (int j = 0; j < 4; j++) {
    int c = lane + 64 * j;
    float mu = cs[c] * (1.0f / NN);
    float var = cs[c + 256] * (1.0f / NN) - mu * mu;
    float xv = x[(size_t)n * HDD + c];
    y[j] = (xv - mu) * rsqrtf(var + 1e-5f) * bg[c] + bb[c];
    m += y[j];
  }
  for (int off = 32; off; off >>= 1) m += __shfl_down(m, off);
  m = __shfl(m, 0) * (1.0f / HDD);
  float var = 0.f;
#pragma unroll
  for (int j = 0; j < 4; j++) { float d = y[j] - m; var += d * d; }
  for (int off = 32; off; off >>= 1) var += __shfl_down(var, off);
  var = __shfl(var, 0) * (1.0f / HDD);
  float inv = rsqrtf(var + 1e-5f);
#pragma unroll
  for (int j = 0; j < 4; j++) {
    int c = lane + 64 * j;
    float z = (y[j] - m) * inv * lg[c] + lb[c];
    z = z > 0.f ? z : expm1f(z);
    out[(size_t)n * HDD + c] = f2b(z);
  }
}

extern "C" void kernel_launch(void* const* d_in, const int* in_sizes, int n_in,
                              void* d_out, int out_size, void* d_ws, size_t ws_size,
                              hipStream_t stream) {
  const float* X   = (const float*)d_in[0];
  const float* H   = (const float*)d_in[1];
  const float* W1  = (const float*)d_in[2];
  const float* W2  = (const float*)d_in[3];
  const float* W3  = (const float*)d_in[4];
  const float* imp = (const float*)d_in[5];
  const float* b3  = (const float*)d_in[8];
  const float* bng = (const float*)d_in[9];
  const float* bnb = (const float*)d_in[10];
  const float* lng = (const float*)d_in[11];
  const float* lnb = (const float*)d_in[12];
  const float* rel = (const float*)d_in[13];
  (void)in_sizes; (void)n_in; (void)out_size; (void)ws_size;

  char* w = (char*)d_ws;
  size_t off = 0;
  auto alloc = [&](size_t bytes) -> void* {
    void* p = w + off;
    off += (bytes + 255) & ~(size_t)255;
    return p;
  };
  float* dvs   = (float*)alloc((size_t)RR * NN * 4);
  float* csbuf = (float*)alloc(512 * 4);
  int* cnt1    = (int*)alloc((size_t)RR * NN * 4);
  int* cnt2    = (int*)alloc((size_t)RR * EE * 4);
  unsigned long long* mask1 = (unsigned long long*)alloc((size_t)RR * NN * 32 * 8);  // 4MB
  unsigned short* idx1 = (unsigned short*)alloc((size_t)RR * NN * S1 * 2);           // 6.3MB
  unsigned short* idx2 = (unsigned short*)alloc((size_t)RR * EE * S2 * 2);           // 5.2MB
  unsigned short* Xdv  = (unsigned short*)alloc(((size_t)RR * NN + 1) * FF * 2);     // 4MB
  unsigned short* t1   = (unsigned short*)alloc(((size_t)RR * EE + 1) * FF * 2);     // 2MB
  unsigned short* Z1   = (unsigned short*)alloc(((size_t)RR * EE + 1) * HDD * 2);    // 4MB
  float* convout       = (float*)alloc((size_t)NN * HDD * 4);                        // 4MB
  unsigned short* Xb   = (unsigned short*)alloc((size_t)NN * HDD * 2);               // 2MB
  unsigned short* hwdv = (unsigned short*)alloc(((size_t)RR * NN + 1) * HDD * 2);    // 8MB
  unsigned short* t2   = (unsigned short*)alloc(((size_t)RR * EE + 1) * HDD * 2);    // 4MB
  unsigned short* ydv  = (unsigned short*)alloc(((size_t)RR * NN + 1) * FF * 2);     // 4MB
  unsigned short* t3   = (unsigned short*)alloc(((size_t)RR * EE + 1) * FF * 2);     // 2MB
  unsigned short* W1catT = (unsigned short*)alloc((size_t)RR * FF * HDD * 2);
  unsigned short* W2T    = (unsigned short*)alloc((size_t)RR * HDD * HDD * 2);
  unsigned short* W3T    = (unsigned short*)alloc((size_t)RR * HDD * FF * 2);

  // ---- prep (3 dispatches) ----
  k_prep1<<<4096 + 2048 + 32, 256, 0, stream>>>(H, rel, W1, W2, W3, imp,
                                                dvs, mask1, idx1, cnt1, W1catT, W2T, W3T, cnt2);
  k_prep2<<<256 + 1024, 256, 0, stream>>>(mask1, cnt2, idx2, X, dvs, Xdv);
  k_prep3<<<32 + 7, 256, 0, stream>>>(cnt2, idx2, Xdv, hwdv, ydv, t1, t2, t3, Z1);

  // ---- layer 1 (128 -> 256) ----
  k_b2s<128><<<2048, 256, 0, stream>>>(cnt2, idx2, Xdv, rel, t1, csbuf);
  k_gemm3<<<dim3(EE / 128, HDD / 128, RR), 256, 0, stream>>>(
      t1, W1catT, FF, FF, RR * FF, (long)EE * FF, FF, Z1, (long)EE * HDD, HDD, nullptr, 0);
  k_b1s256<<<NN, 256, 0, stream>>>(cnt1, idx1, Z1, dvs, convout);
  k_stats<<<NN / 32, 256, 0, stream>>>(convout, csbuf);
  k_bnlnelu<<<NN / 4, 256, 0, stream>>>(convout, csbuf, bng, bnb, lng, lnb, Xb);

  // ---- layer 2 (256 -> 256), W2 applied first ----
  k_gemm3<<<dim3(NN / 128, HDD / 128, RR), 256, 0, stream>>>(
      Xb, W2T, HDD, HDD, HDD, 0, (long)HDD * HDD, hwdv, (long)NN * HDD, HDD, dvs, NN);
  k_b2s<256><<<2048, 256, 0, stream>>>(cnt2, idx2, hwdv, rel, t2, csbuf);
  k_b1s256<<<NN, 256, 0, stream>>>(cnt1, idx1, t2, dvs, convout);
  k_stats<<<NN / 32, 256, 0, stream>>>(convout, csbuf);
  k_bnlnelu<<<NN / 4, 256, 0, stream>>>(convout, csbuf, bng + HDD, bnb + HDD, lng + HDD, lnb + HDD, Xb);

  // ---- layer 3 (256 -> 128), W3 applied first ----
  k_gemm3<<<dim3(NN / 128, 1, RR), 256, 0, stream>>>(
      Xb, W3T, HDD, HDD, HDD, 0, (long)FF * HDD, ydv, (long)NN * FF, FF, dvs, NN);
  k_b2s<128><<<2048, 256, 0, stream>>>(cnt2, idx2, ydv, rel, t3, csbuf);
  k_b1s128o<<<NN, 256, 0, stream>>>(cnt1, idx1, t3, dvs, X, b3, (float*)d_out);
}

// Round 8
// 556.285 us; speedup vs baseline: 1.5644x; 1.0157x over previous
//
#include <hip/hip_runtime.h>
#include <hip/hip_bf16.h>

#define NN 4096
#define EE 2048
#define RR 4
#define FF 128
#define HDD 256
#define S1 192
#define S2 320

typedef __attribute__((ext_vector_type(4))) float floatx4;
typedef __attribute__((ext_vector_type(8))) __bf16 bf16x8;
typedef __attribute__((ext_vector_type(8))) unsigned short u16x8;

#define AS1 __attribute__((address_space(1)))
#define AS3 __attribute__((address_space(3)))

__device__ __forceinline__ void async16(const void* g, void* l) {
  __builtin_amdgcn_global_load_lds((const AS1 void*)(unsigned long long)(g),
                                   (AS3 void*)(unsigned int)(unsigned long long)(l),
                                   16, 0, 0);
}

__device__ inline unsigned short f2b(float x) {
  unsigned int u = __float_as_uint(x);
  unsigned int r = u + 0x7fffu + ((u >> 16) & 1u);
  return (unsigned short)(r >> 16);
}

__device__ inline float rel_w(const float* rel, int r) {
  float m = fmaxf(fmaxf(rel[0], rel[1]), fmaxf(rel[2], rel[3]));
  float s = 0.f;
#pragma unroll
  for (int i = 0; i < RR; i++) s += expf(rel[i] - m);
  return expf(rel[r] - m) / s;
}

// ==== prep1: {H scan -> dvs, mask1, csr1 (padded e-lists, >=24) | wprep | zero cnt2} ====
__global__ void k_prep1(const float* __restrict__ H, const float* __restrict__ rel,
                        const float* __restrict__ W1, const float* __restrict__ W2,
                        const float* __restrict__ W3, const float* __restrict__ imp,
                        float* __restrict__ dvs, unsigned long long* __restrict__ mask,
                        unsigned short* __restrict__ idx1, int* __restrict__ cnt1,
                        unsigned short* __restrict__ W1catT, unsigned short* __restrict__ W2T,
                        unsigned short* __restrict__ W3T, int* __restrict__ cnt2) {
  int b = blockIdx.x;
  if (b < 4096) {
    int wave = (b << 2) | (threadIdx.x >> 6);  // = r*NN + n
    int lane = threadIdx.x & 63;
    int r = wave >> 12;
    const float* row = H + (size_t)wave * EE;
    unsigned long long* mrow = mask + (size_t)wave * 32;
    unsigned short* list = idx1 + (size_t)wave * S1;
    int tot = 0;
    for (int j = 0; j < 32; j++) {
      float h = row[j * 64 + lane];
      unsigned long long m = __ballot(h != 0.0f);
      if (lane == 0) mrow[j] = m;
      if (h != 0.0f) {
        int pos = tot + __popcll(m & ((1ull << lane) - 1ull));
        if (pos < S1) list[pos] = (unsigned short)(j * 64 + lane);
      }
      tot += __popcll(m);
    }
    int tc = tot < S1 ? tot : S1;
    int padded = (tc + 7) & ~7;
    if (padded < 24) padded = 24;
    unsigned short padE = (unsigned short)((RR - r) << 11);  // -> global zero e-row
    if (lane < padded - tc) list[tc + lane] = padE;
    if (lane == 0) {
      cnt1[wave] = tc;
      float rwr = rel_w(rel, r);
      dvs[wave] = rwr * rsqrtf(rwr * (float)tot + 1e-8f);
    }
  } else if (b < 4096 + 2048) {
    int idx = (b - 4096) * 256 + threadIdx.x;
    if (idx < RR * FF * HDD) {
      int o = idx % HDD, f = (idx / HDD) % FF, r = idx / (HDD * FF);
      float sg = 1.0f / (1.0f + expf(-imp[r]));
      W1catT[(size_t)o * (RR * FF) + r * FF + f] = f2b(sg * W1[((size_t)r * FF + f) * HDD + o]);
    } else if (idx < RR * FF * HDD + RR * HDD * HDD) {
      int j = idx - RR * FF * HDD;
      int c = j % HDD, o = (j / HDD) % HDD, r = j / (HDD * HDD);
      float sg = 1.0f / (1.0f + expf(-imp[RR + r]));
      W2T[j] = f2b(sg * W2[((size_t)r * HDD + c) * HDD + o]);
    } else {
      int j = idx - RR * FF * HDD - RR * HDD * HDD;
      int c = j % HDD, o = (j / HDD) % FF, r = j / (HDD * FF);
      float sg = 1.0f / (1.0f + expf(-imp[2 * RR + r]));
      W3T[j] = f2b(sg * W3[((size_t)r * HDD + c) * FF + o]);
    }
  } else {
    int i = (b - 6144) * 256 + threadIdx.x;
    if (i < RR * EE) cnt2[i] = 0;
  }
}

// ==== prep2: {mask1 bit-transpose -> csr2 scatter (atomic offsets) | Xdv build} ====
__global__ void k_prep2(const unsigned long long* __restrict__ m1, int* __restrict__ cnt2,
                        unsigned short* __restrict__ idx2, const float* __restrict__ X,
                        const float* __restrict__ dvs, unsigned short* __restrict__ Xdv) {
  __shared__ unsigned long long w[64 * 33];
  int t = threadIdx.x;
  if (blockIdx.x < 256) {
    int r = blockIdx.x >> 6;
    int n0 = (blockIdx.x & 63) << 6;
    const unsigned long long* src = m1 + ((size_t)(r << 12) + n0) * 32;
#pragma unroll
    for (int i = 0; i < 8; i++) {
      int idx = t + i * 256;
      int n = idx >> 5, W = idx & 31;
      w[n * 33 + W] = src[idx];
    }
    __syncthreads();
    int wid = t >> 6, lane = t & 63;
#pragma unroll
    for (int Wi = 0; Wi < 8; Wi++) {
      int W = wid * 8 + Wi;
      unsigned long long myw = w[lane * 33 + W];
      unsigned long long out = 0;
      for (int bb = 0; bb < 64; bb++) {
        unsigned long long mm = __ballot(((myw >> bb) & 1ull) != 0);
        if (lane == bb) out = mm;
      }
      if (out) {
        int e = W * 64 + lane;
        int rowid = (r << 11) + e;
        int c = __popcll(out);
        int off = atomicAdd(&cnt2[rowid], c);
        unsigned long long bb2 = out;
        while (bb2) {
          int l = __builtin_ctzll(bb2);
          bb2 &= bb2 - 1;
          if (off < S2) idx2[(size_t)rowid * S2 + off] = (unsigned short)(n0 + l);
          off++;
        }
      }
    }
  } else {
    int g = (blockIdx.x - 256) * 256 + t;        // 0..262143
    int f8 = g & 15, n = (g >> 4) & (NN - 1), r = g >> 16;
    const float* xp = X + (size_t)n * FF + (f8 << 3);
    float4 v0 = *(const float4*)xp;
    float4 v1 = *(const float4*)(xp + 4);
    float d = dvs[(r << 12) + n];
    ushort4 o0, o1;
    o0.x = f2b(v0.x * d); o0.y = f2b(v0.y * d); o0.z = f2b(v0.z * d); o0.w = f2b(v0.w * d);
    o1.x = f2b(v1.x * d); o1.y = f2b(v1.y * d); o1.z = f2b(v1.z * d); o1.w = f2b(v1.w * d);
    unsigned short* dp = Xdv + ((size_t)(r << 12) + n) * FF + (f8 << 3);
    *(ushort4*)dp = o0;
    *(ushort4*)(dp + 4) = o1;
  }
}

// ==== prep3: {pad csr2 lists (>=24) | zero the single pad rows} ====
__global__ void k_prep3(int* __restrict__ cnt2, unsigned short* __restrict__ idx2,
                        unsigned short* __restrict__ Xdv, unsigned short* __restrict__ hwdv,
                        unsigned short* __restrict__ ydv, unsigned short* __restrict__ t1,
                        unsigned short* __restrict__ t2, unsigned short* __restrict__ t3,
                        unsigned short* __restrict__ Z1) {
  int b = blockIdx.x, t = threadIdx.x;
  if (b < 32) {
    int row = (b << 8) + t;          // 0..8191 = r*EE + e
    int r = row >> 11;
    int cnt = cnt2[row];
    if (cnt > S2) { cnt = S2; cnt2[row] = S2; }
    int padded = (cnt + 7) & ~7;
    if (padded < 24) padded = 24;
    unsigned short pv = (unsigned short)((RR - r) << 12);  // -> global zero n-row
    for (int i = cnt; i < padded; i++) idx2[(size_t)row * S2 + i] = pv;
  } else {
    int q = b - 32;
    unsigned short* p; int C;
    switch (q) {
      case 0: p = Xdv  + (size_t)(RR * NN) * FF;  C = FF;  break;
      case 1: p = hwdv + (size_t)(RR * NN) * HDD; C = HDD; break;
      case 2: p = ydv  + (size_t)(RR * NN) * FF;  C = FF;  break;
      case 3: p = t1   + (size_t)(RR * EE) * FF;  C = FF;  break;
      case 4: p = t2   + (size_t)(RR * EE) * HDD; C = HDD; break;
      case 5: p = t3   + (size_t)(RR * EE) * FF;  C = FF;  break;
      default: p = Z1  + (size_t)(RR * EE) * HDD; C = HDD; break;
    }
    if (t < C) p[t] = 0;
  }
}

// ---------------- dense MFMA GEMM, 128x128 tile, BK=64, single-barrier dbuf (R4-proven) ----------------
__global__ __launch_bounds__(256) void k_gemm3(
    const unsigned short* __restrict__ A, const unsigned short* __restrict__ BT,
    int K, int lda, int ldb, long a_rs, long b_rs,
    unsigned short* __restrict__ P, long c_rs, int ldc,
    const float* __restrict__ rscale, long rs_rs) {
  __shared__ unsigned short Al[2][128 * 64];
  __shared__ unsigned short Bl[2][128 * 64];
  int tid = threadIdx.x, wid = tid >> 6, lane = tid & 63;
  int m0 = blockIdx.x << 7, n0 = blockIdx.y << 7;
  int zr = blockIdx.z;
  int r8 = lane >> 3, c8 = lane & 7;
  int swz = ((c8 ^ r8) << 3);
  const unsigned short* Ab = A + (size_t)zr * a_rs + (size_t)m0 * lda;
  const unsigned short* Bb = BT + (size_t)zr * b_rs + (size_t)n0 * ldb;
  auto stage = [&](int pb, int k0) {
#pragma unroll
    for (int t = 0; t < 4; t++) {
      int rbase = (wid << 5) + (t << 3);
      int row = rbase + r8;
      async16(Ab + (size_t)row * lda + k0 + swz, &Al[pb][rbase * 64 + lane * 8]);
      async16(Bb + (size_t)row * ldb + k0 + swz, &Bl[pb][rbase * 64 + lane * 8]);
    }
  };
  int wm = (wid >> 1) << 6, wn = (wid & 1) << 6;
  int fm = lane & 15, quad = lane >> 4;
  int f7 = fm & 7;
  floatx4 acc[4][4];
#pragma unroll
  for (int i = 0; i < 4; i++)
#pragma unroll
    for (int j = 0; j < 4; j++) acc[i][j] = (floatx4){0.f, 0.f, 0.f, 0.f};
  auto compute = [&](int pb) {
#pragma unroll
    for (int ks = 0; ks < 2; ks++) {
      int kg = (ks << 2) | quad;
      int ko = ((kg ^ f7) << 3);
      bf16x8 a[4], b[4];
#pragma unroll
      for (int i = 0; i < 4; i++) {
        a[i] = *(const bf16x8*)&Al[pb][(wm + i * 16 + fm) * 64 + ko];
        b[i] = *(const bf16x8*)&Bl[pb][(wn + i * 16 + fm) * 64 + ko];
      }
#pragma unroll
      for (int i = 0; i < 4; i++)
#pragma unroll
        for (int j = 0; j < 4; j++)
          acc[i][j] = __builtin_amdgcn_mfma_f32_16x16x32_bf16(a[i], b[j], acc[i][j], 0, 0, 0);
    }
  };
  stage(0, 0);
  __syncthreads();
  for (int k0 = 0; k0 < K; k0 += 128) {
    if (k0 + 64 < K) stage(1, k0 + 64);
    compute(0);
    __syncthreads();
    if (k0 + 128 < K) stage(0, k0 + 128);
    compute(1);
    __syncthreads();
  }
  unsigned short* Cb = P + (size_t)zr * c_rs;
#pragma unroll
  for (int mi = 0; mi < 4; mi++)
#pragma unroll
    for (int v = 0; v < 4; v++) {
      int row = m0 + wm + mi * 16 + quad * 4 + v;
      float rs = rscale ? rscale[(size_t)zr * rs_rs + row] : 1.0f;
#pragma unroll
      for (int ni = 0; ni < 4; ni++) {
        int col = n0 + wn + ni * 16 + fm;
        Cb[(size_t)row * ldc + col] = f2b(acc[mi][ni][v] * rs);
      }
    }
}

// ---------------- sparse gather, B2 side: out[(r,e)][C] = de2 * sum_{n in csr2 row} T[(r,n)][C] ----
// XCD-sliced: r = (bid%8)>>1 so each XCD's gathers stay in one r's table slice (L2-resident).
// 2-deep data / 4-ahead index software pipeline; pads hit the zeroed row.
template <int C>
__global__ __launch_bounds__(256) void k_b2s(
    const int* __restrict__ cnt2, const unsigned short* __restrict__ idx2,
    const unsigned short* __restrict__ T, const float* __restrict__ rel,
    unsigned short* __restrict__ out, float* __restrict__ csz) {
  if (blockIdx.x == 0) {
#pragma unroll
    for (int i = 0; i < 16; i++) csz[i * 256 + threadIdx.x] = 0.f;
  }
  int wid = threadIdx.x >> 6, lane = threadIdx.x & 63;
  int bid = blockIdx.x;
  int xcd = bid & 7;
  int r = xcd >> 1;
  int e = ((xcd & 1) << 10) + ((bid >> 3) << 2) + wid;
  int wv = (r << 11) + e;
  int cnt = cnt2[wv];
  const unsigned short* list = idx2 + (size_t)wv * S2;
  const unsigned short* Tb = T + ((size_t)(r << 12)) * C;
  int lo = (C == 256) ? (lane << 2) : (lane << 1);
  float a0 = 0.f, a1 = 0.f, a2 = 0.f, a3 = 0.f;
  int nb = (cnt + 7) >> 3;
  if (nb < 3) nb = 3;
  uint2 u[8], v[8];
  auto LIDX = [&](int bo) { return *(const u16x8*)(list + (bo << 3)); };
  auto GATH = [&](uint2 (&d)[8], u16x8 I) {
#pragma unroll
    for (int k = 0; k < 8; k++) {
      const unsigned short* p = Tb + (size_t)((unsigned short)I[k]) * C + lo;
      if (C == 256) d[k] = *(const uint2*)p;
      else d[k].x = *(const unsigned int*)p;
    }
  };
  auto ACCU = [&](uint2 (&d)[8]) {
#pragma unroll
    for (int k = 0; k < 8; k++) {
      a0 += __uint_as_float(d[k].x << 16);
      a1 += __uint_as_float(d[k].x & 0xffff0000u);
      if (C == 256) {
        a2 += __uint_as_float(d[k].y << 16);
        a3 += __uint_as_float(d[k].y & 0xffff0000u);
      }
    }
  };
  u16x8 iA = LIDX(0), iB = LIDX(1);
  GATH(u, iA);
  iA = LIDX(2);
  GATH(v, iB);
  iB = LIDX(3 < nb - 1 ? 3 : nb - 1);
  for (int b = 0; b < nb; b += 2) {
    ACCU(u);
    if (b + 2 < nb) GATH(u, iA);
    if (b + 4 < nb) iA = LIDX(b + 4);
    if (b + 1 < nb) {
      ACCU(v);
      if (b + 3 < nb) GATH(v, iB);
      if (b + 5 < nb) iB = LIDX(b + 5);
    }
  }
  float rwr = rel_w(rel, r);
  float s = 1.0f / (rwr * (float)cnt + 1e-8f);
  unsigned short* op = out + (size_t)wv * C;
  if (C == 256) {
    ushort4 o;
    o.x = f2b(a0 * s); o.y = f2b(a1 * s); o.z = f2b(a2 * s); o.w = f2b(a3 * s);
    *(ushort4*)(op + (lane << 2)) = o;
  } else {
    ushort2 o;
    o.x = f2b(a0 * s); o.y = f2b(a1 * s);
    *(ushort2*)(op + (lane << 1)) = o;
  }
}

// ---------------- sparse gather, B1 side, C=256, + fused BN stats (8-replica csbuf) ----------------
__global__ __launch_bounds__(256) void k_b1s256(
    const int* __restrict__ cnt1, const unsigned short* __restrict__ idx1,
    const unsigned short* __restrict__ T, const float* __restrict__ dvs,
    float* __restrict__ out, float* __restrict__ csbuf) {
  __shared__ float sm[4][256];
  int wid = threadIdx.x >> 6, lane = threadIdx.x & 63;
  int n = blockIdx.x;
  int rn = (wid << 12) + n;
  int cnt = cnt1[rn];
  const unsigned short* list = idx1 + (size_t)rn * S1;
  const unsigned short* Tb = T + ((size_t)(wid << 11)) * 256;
  float a0 = 0.f, a1 = 0.f, a2 = 0.f, a3 = 0.f;
  int nb = (cnt + 7) >> 3;
  if (nb < 3) nb = 3;
  uint2 u[8], v[8];
  auto LIDX = [&](int bo) { return *(const u16x8*)(list + (bo << 3)); };
  auto GATH = [&](uint2 (&d)[8], u16x8 I) {
#pragma unroll
    for (int k = 0; k < 8; k++)
      d[k] = *(const uint2*)(Tb + (size_t)((unsigned short)I[k]) * 256 + (lane << 2));
  };
  auto ACCU = [&](uint2 (&d)[8]) {
#pragma unroll
    for (int k = 0; k < 8; k++) {
      a0 += __uint_as_float(d[k].x << 16);
      a1 += __uint_as_float(d[k].x & 0xffff0000u);
      a2 += __uint_as_float(d[k].y << 16);
      a3 += __uint_as_float(d[k].y & 0xffff0000u);
    }
  };
  u16x8 iA = LIDX(0), iB = LIDX(1);
  GATH(u, iA);
  iA = LIDX(2);
  GATH(v, iB);
  iB = LIDX(3 < nb - 1 ? 3 : nb - 1);
  for (int b = 0; b < nb; b += 2) {
    ACCU(u);
    if (b + 2 < nb) GATH(u, iA);
    if (b + 4 < nb) iA = LIDX(b + 4);
    if (b + 1 < nb) {
      ACCU(v);
      if (b + 3 < nb) GATH(v, iB);
      if (b + 5 < nb) iB = LIDX(b + 5);
    }
  }
  float dv = dvs[rn];
  float4 yv = {dv * a0, dv * a1, dv * a2, dv * a3};
  *(float4*)&sm[wid][lane << 2] = yv;
  __syncthreads();
  int c = threadIdx.x;
  float y = sm[0][c] + sm[1][c] + sm[2][c] + sm[3][c];
  out[(size_t)n * HDD + c] = y;
  float* csb = csbuf + ((blockIdx.x & 7) << 9);
  atomicAdd(&csb[c], y);
  atomicAdd(&csb[c + 256], y * y);
}

// ---------------- sparse gather, B1 side, C=128, FINAL: d_out = X + b3 + sum_r dv * gather ----------------
__global__ __launch_bounds__(256) void k_b1s128o(
    const int* __restrict__ cnt1, const unsigned short* __restrict__ idx1,
    const unsigned short* __restrict__ T, const float* __restrict__ dvs,
    const float* __restrict__ X, const float* __restrict__ b3, float* __restrict__ out) {
  __shared__ float sm[4][128];
  int wid = threadIdx.x >> 6, lane = threadIdx.x & 63;
  int n = blockIdx.x;
  int rn = (wid << 12) + n;
  int cnt = cnt1[rn];
  const unsigned short* list = idx1 + (size_t)rn * S1;
  const unsigned short* Tb = T + ((size_t)(wid << 11)) * 128;
  float a0 = 0.f, a1 = 0.f;
  int nb = (cnt + 7) >> 3;
  if (nb < 3) nb = 3;
  unsigned int u[8], v[8];
  auto LIDX = [&](int bo) { return *(const u16x8*)(list + (bo << 3)); };
  auto GATH = [&](unsigned int (&d)[8], u16x8 I) {
#pragma unroll
    for (int k = 0; k < 8; k++)
      d[k] = *(const unsigned int*)(Tb + (size_t)((unsigned short)I[k]) * 128 + (lane << 1));
  };
  auto ACCU = [&](unsigned int (&d)[8]) {
#pragma unroll
    for (int k = 0; k < 8; k++) {
      a0 += __uint_as_float(d[k] << 16);
      a1 += __uint_as_float(d[k] & 0xffff0000u);
    }
  };
  u16x8 iA = LIDX(0), iB = LIDX(1);
  GATH(u, iA);
  iA = LIDX(2);
  GATH(v, iB);
  iB = LIDX(3 < nb - 1 ? 3 : nb - 1);
  for (int b = 0; b < nb; b += 2) {
    ACCU(u);
    if (b + 2 < nb) GATH(u, iA);
    if (b + 4 < nb) iA = LIDX(b + 4);
    if (b + 1 < nb) {
      ACCU(v);
      if (b + 3 < nb) GATH(v, iB);
      if (b + 5 < nb) iB = LIDX(b + 5);
    }
  }
  float dv = dvs[rn];
  float2 yv = {dv * a0, dv * a1};
  *(float2*)&sm[wid][lane << 1] = yv;
  __syncthreads();
  int t = threadIdx.x;
  if (t < 128) {
    float y = sm[0][t] + sm[1][t] + sm[2][t] + sm[3][t];
    out[(size_t)n * FF + t] = X[(size_t)n * FF + t] + b3[t] + y;
  }
}

// ---- BN (batch stats from 8-replica csbuf) -> LN -> ELU -> bf16 [NN][HDD] ----
__global__ void k_bnlnelu(const float* __restrict__ x, const float* __restrict__ csbuf,
                          const float* __restrict__ bg, const float* __restrict__ bb,
                          const float* __restrict__ lg, const float* __restrict__ lb,
                          unsigned short* __restrict__ out) {
  int wid = threadIdx.x >> 6, lane = threadIdx.x & 63;
  int n = blockIdx.x * 4 + wid;
  float y[4];
  float m = 0.f;
#pragma unroll
  for (int j = 0; j < 4; j++) {
    int c = lane + 64 * j;
    float s0 = 0.f, s1 = 0.f;
#pragma unroll
    for (int k = 0; k < 8; k++) {
      s0 += csbuf[k * 512 + c];
      s1 += csbuf[k * 512 + 256 + c];
    }
    float mu = s0 * (1.0f / NN);
    float var = s1 * (1.0f / NN) - mu * mu;
    float xv = x[(size_t)n * HDD + c];
    y[j] = (xv - mu) * rsqrtf(var + 1e-5f) * bg[c] + bb[c];
    m += y[j];
  }
  for (int off = 32; off; off >>= 1) m += __shfl_down(m, off);
  m = __shfl(m, 0) * (1.0f / HDD);
  float var = 0.f;
#pragma unroll
  for (int j = 0; j < 4; j++) { float d = y[j] - m; var += d * d; }
  for (int off = 32; off; off >>= 1) var += __shfl_down(var, off);
  var = __shfl(var, 0) * (1.0f / HDD);
  float inv = rsqrtf(var + 1e-5f);
#pragma unroll
  for (int j = 0; j < 4; j++) {
    int c = lane + 64 * j;
    float z = (y[j] - m) * inv * lg[c] + lb[c];
    z = z > 0.f ? z : expm1f(z);
    out[(size_t)n * HDD + c] = f2b(z);
  }
}

extern "C" void kernel_launch(void* const* d_in, const int* in_sizes, int n_in,
                              void* d_out, int out_size, void* d_ws, size_t ws_size,
                              hipStream_t stream) {
  const float* X   = (const float*)d_in[0];
  const float* H   = (const float*)d_in[1];
  const float* W1  = (const float*)d_in[2];
  const float* W2  = (const float*)d_in[3];
  const float* W3  = (const float*)d_in[4];
  const float* imp = (const float*)d_in[5];
  const float* b3  = (const float*)d_in[8];
  const float* bng = (const float*)d_in[9];
  const float* bnb = (const float*)d_in[10];
  const float* lng = (const float*)d_in[11];
  const float* lnb = (const float*)d_in[12];
  const float* rel = (const float*)d_in[13];
  (void)in_sizes; (void)n_in; (void)out_size; (void)ws_size;

  char* w = (char*)d_ws;
  size_t off = 0;
  auto alloc = [&](size_t bytes) -> void* {
    void* p = w + off;
    off += (bytes + 255) & ~(size_t)255;
    return p;
  };
  float* dvs   = (float*)alloc((size_t)RR * NN * 4);
  float* csbuf = (float*)alloc(8 * 512 * 4);
  int* cnt1    = (int*)alloc((size_t)RR * NN * 4);
  int* cnt2    = (int*)alloc((size_t)RR * EE * 4);
  unsigned long long* mask1 = (unsigned long long*)alloc((size_t)RR * NN * 32 * 8);  // 4MB
  unsigned short* idx1 = (unsigned short*)alloc((size_t)RR * NN * S1 * 2);           // 6.3MB
  unsigned short* idx2 = (unsigned short*)alloc((size_t)RR * EE * S2 * 2);           // 5.2MB
  unsigned short* Xdv  = (unsigned short*)alloc(((size_t)RR * NN + 1) * FF * 2);     // 4MB
  unsigned short* t1   = (unsigned short*)alloc(((size_t)RR * EE + 1) * FF * 2);     // 2MB
  unsigned short* Z1   = (unsigned short*)alloc(((size_t)RR * EE + 1) * HDD * 2);    // 4MB
  float* convout       = (float*)alloc((size_t)NN * HDD * 4);                        // 4MB
  unsigned short* Xb   = (unsigned short*)alloc((size_t)NN * HDD * 2);               // 2MB
  unsigned short* hwdv = (unsigned short*)alloc(((size_t)RR * NN + 1) * HDD * 2);    // 8MB
  unsigned short* t2   = (unsigned short*)alloc(((size_t)RR * EE + 1) * HDD * 2);    // 4MB
  unsigned short* ydv  = (unsigned short*)alloc(((size_t)RR * NN + 1) * FF * 2);     // 4MB
  unsigned short* t3   = (unsigned short*)alloc(((size_t)RR * EE + 1) * FF * 2);     // 2MB
  unsigned short* W1catT = (unsigned short*)alloc((size_t)RR * FF * HDD * 2);
  unsigned short* W2T    = (unsigned short*)alloc((size_t)RR * HDD * HDD * 2);
  unsigned short* W3T    = (unsigned short*)alloc((size_t)RR * HDD * FF * 2);

  // ---- prep (3 dispatches) ----
  k_prep1<<<4096 + 2048 + 32, 256, 0, stream>>>(H, rel, W1, W2, W3, imp,
                                                dvs, mask1, idx1, cnt1, W1catT, W2T, W3T, cnt2);
  k_prep2<<<256 + 1024, 256, 0, stream>>>(mask1, cnt2, idx2, X, dvs, Xdv);
  k_prep3<<<32 + 7, 256, 0, stream>>>(cnt2, idx2, Xdv, hwdv, ydv, t1, t2, t3, Z1);

  // ---- layer 1 (128 -> 256) ----
  k_b2s<128><<<2048, 256, 0, stream>>>(cnt2, idx2, Xdv, rel, t1, csbuf);
  k_gemm3<<<dim3(EE / 128, HDD / 128, RR), 256, 0, stream>>>(
      t1, W1catT, FF, FF, RR * FF, (long)EE * FF, FF, Z1, (long)EE * HDD, HDD, nullptr, 0);
  k_b1s256<<<NN, 256, 0, stream>>>(cnt1, idx1, Z1, dvs, convout, csbuf);
  k_bnlnelu<<<NN / 4, 256, 0, stream>>>(convout, csbuf, bng, bnb, lng, lnb, Xb);

  // ---- layer 2 (256 -> 256), W2 applied first ----
  k_gemm3<<<dim3(NN / 128, HDD / 128, RR), 256, 0, stream>>>(
      Xb, W2T, HDD, HDD, HDD, 0, (long)HDD * HDD, hwdv, (long)NN * HDD, HDD, dvs, NN);
  k_b2s<256><<<2048, 256, 0, stream>>>(cnt2, idx2, hwdv, rel, t2, csbuf);
  k_b1s256<<<NN, 256, 0, stream>>>(cnt1, idx1, t2, dvs, convout, csbuf);
  k_bnlnelu<<<NN / 4, 256, 0, stream>>>(convout, csbuf, bng + HDD, bnb + HDD, lng + HDD, lnb + HDD, Xb);

  // ---- layer 3 (256 -> 128), W3 applied first ----
  k_gemm3<<<dim3(NN / 128, 1, RR), 256, 0, stream>>>(
      Xb, W3T, HDD, HDD, HDD, 0, (long)FF * HDD, ydv, (long)NN * FF, FF, dvs, NN);
  k_b2s<128><<<2048, 256, 0, stream>>>(cnt2, idx2, ydv, rel, t3, csbuf);
  k_b1s128o<<<NN, 256, 0, stream>>>(cnt1, idx1, t3, dvs, X, b3, (float*)d_out);
}

// Round 9
// 477.262 us; speedup vs baseline: 1.8235x; 1.1656x over previous
//
#include <hip/hip_runtime.h>
#include <hip/hip_bf16.h>

#define NN 4096
#define EE 2048
#define RR 4
#define FF 128
#define HDD 256

typedef __attribute__((ext_vector_type(4))) float floatx4;
typedef __attribute__((ext_vector_type(8))) __bf16 bf16x8;

#define AS1 __attribute__((address_space(1)))
#define AS3 __attribute__((address_space(3)))

__device__ __forceinline__ void async16(const void* g, void* l) {
  __builtin_amdgcn_global_load_lds((const AS1 void*)(unsigned long long)(g),
                                   (AS3 void*)(unsigned int)(unsigned long long)(l),
                                   16, 0, 0);
}

__device__ inline unsigned short f2b(float x) {
  unsigned int u = __float_as_uint(x);
  unsigned int r = u + 0x7fffu + ((u >> 16) & 1u);
  return (unsigned short)(r >> 16);
}
__device__ inline float b2f(unsigned short u) { return __uint_as_float((unsigned int)u << 16); }

__device__ inline float rel_w(const float* rel, int r) {
  float m = fmaxf(fmaxf(rel[0], rel[1]), fmaxf(rel[2], rel[3]));
  float s = 0.f;
#pragma unroll
  for (int i = 0; i < RR; i++) s += expf(rel[i] - m);
  return expf(rel[r] - m) / s;
}

// ==== prep1: fused {dvmask (float4, convention-P mask) | wprep | zero(de,cs)} ====
// Convention P: bit l of word W=jj*4+c  <->  e = jj*256 + l*4 + c
__global__ void k_prep1(const float* __restrict__ H, const float* __restrict__ rel,
                        const float* __restrict__ W1, const float* __restrict__ W2,
                        const float* __restrict__ W3, const float* __restrict__ imp,
                        float* __restrict__ dvs, unsigned long long* __restrict__ mask,
                        unsigned short* __restrict__ W1catT, unsigned short* __restrict__ W2T,
                        unsigned short* __restrict__ W3T, float* __restrict__ de, float* __restrict__ cs) {
  int b = blockIdx.x;
  if (b < 4096) {
    int wave = (b << 2) | (threadIdx.x >> 6);  // = r*NN + n
    int lane = threadIdx.x & 63;
    int r = wave >> 12;
    const float4* row = (const float4*)(H + (size_t)wave * EE);
    unsigned long long* mrow = mask + (size_t)wave * 32;
    float s = 0.f;
#pragma unroll
    for (int jj = 0; jj < 8; jj++) {
      float4 v = row[jj * 64 + lane];
      s += v.x + v.y + v.z + v.w;
      unsigned long long m0 = __ballot(v.x != 0.0f);
      unsigned long long m1 = __ballot(v.y != 0.0f);
      unsigned long long m2 = __ballot(v.z != 0.0f);
      unsigned long long m3 = __ballot(v.w != 0.0f);
      if (lane == 0) {
        mrow[jj * 4 + 0] = m0;
        mrow[jj * 4 + 1] = m1;
        mrow[jj * 4 + 2] = m2;
        mrow[jj * 4 + 3] = m3;
      }
    }
    for (int off = 32; off; off >>= 1) s += __shfl_down(s, off);
    if (lane == 0) {
      float rwr = rel_w(rel, r);
      dvs[wave] = rwr * rsqrtf(rwr * s + 1e-8f);
    }
  } else if (b < 4096 + 2048) {
    int idx = (b - 4096) * 256 + threadIdx.x;
    if (idx < RR * FF * HDD) {
      int o = idx % HDD, f = (idx / HDD) % FF, r = idx / (HDD * FF);
      float sg = 1.0f / (1.0f + expf(-imp[r]));
      W1catT[(size_t)o * (RR * FF) + r * FF + f] = f2b(sg * W1[((size_t)r * FF + f) * HDD + o]);
    } else if (idx < RR * FF * HDD + RR * HDD * HDD) {
      int j = idx - RR * FF * HDD;
      int c = j % HDD, o = (j / HDD) % HDD, r = j / (HDD * HDD);
      float sg = 1.0f / (1.0f + expf(-imp[RR + r]));
      W2T[j] = f2b(sg * W2[((size_t)r * HDD + c) * HDD + o]);
    } else {
      int j = idx - RR * FF * HDD - RR * HDD * HDD;
      int c = j % HDD, o = (j / HDD) % FF, r = j / (HDD * FF);
      float sg = 1.0f / (1.0f + expf(-imp[2 * RR + r]));
      W3T[j] = f2b(sg * W3[((size_t)r * HDD + c) * FF + o]);
    }
  } else {
    int i = (b - 6144) * 256 + threadIdx.x;
    if (i < RR * EE) de[i] = 0.f;
    else if (i < RR * EE + 2 * HDD) cs[i - RR * EE] = 0.f;
  }
}

// ==== prep2: fused {maskT (P-convention bit-transpose -> canonical mask2 + de counts) | cvtTs} ====
__global__ void k_prep2(const unsigned long long* __restrict__ m1, unsigned long long* __restrict__ m2,
                        float* __restrict__ de, const float* __restrict__ X,
                        const float* __restrict__ dvs, unsigned short* __restrict__ XdvT) {
  __shared__ unsigned long long w[64 * 33];
  __shared__ unsigned short tile[64][65];
  int t = threadIdx.x;
  if (blockIdx.x < 256) {
    int r = blockIdx.x >> 6;
    int n0 = (blockIdx.x & 63) << 6;
    const unsigned long long* src = m1 + ((size_t)(r << 12) + n0) * 32;
#pragma unroll
    for (int i = 0; i < 8; i++) {
      int idx = t + i * 256;
      int n = idx >> 5, W = idx & 31;
      w[n * 33 + W] = src[idx];
    }
    __syncthreads();
    int wid = t >> 6, lane = t & 63;
    int v = n0 >> 6;
#pragma unroll
    for (int Wi = 0; Wi < 8; Wi++) {
      int W = wid * 8 + Wi;
      unsigned long long myw = w[lane * 33 + W];
      unsigned long long out = 0;
      for (int bb = 0; bb < 64; bb++) {
        unsigned long long mm = __ballot(((myw >> bb) & 1ull) != 0);
        if (lane == bb) out = mm;
      }
      // convention P: bit 'lane' of word W  <->  e = (W>>2)*256 + lane*4 + (W&3)
      int e = ((W >> 2) << 8) + (lane << 2) + (W & 3);
      m2[((size_t)r * EE + e) * 64 + v] = out;
      atomicAdd(&de[r * EE + e], (float)__popcll(out));
    }
  } else {
    int idx = blockIdx.x - 256;
    int c0 = (idx & 1) * 64, m0 = ((idx >> 1) & 63) * 64, r = idx >> 7;
    int tr = t >> 4, tc = t & 15;
#pragma unroll
    for (int i = 0; i < 4; i++) {
      int m = m0 + tr + 16 * i;
      float d = dvs[(size_t)r * NN + m];
      float4 v = *(const float4*)(X + (size_t)m * FF + c0 + tc * 4);
      tile[tr + 16 * i][tc * 4 + 0] = f2b(v.x * d);
      tile[tr + 16 * i][tc * 4 + 1] = f2b(v.y * d);
      tile[tr + 16 * i][tc * 4 + 2] = f2b(v.z * d);
      tile[tr + 16 * i][tc * 4 + 3] = f2b(v.w * d);
    }
    __syncthreads();
    unsigned short* db = XdvT + (size_t)r * FF * NN;
#pragma unroll
    for (int i = 0; i < 4; i++) {
      int c = c0 + tr + 16 * i;
      ushort4 v;
      v.x = tile[tc * 4 + 0][tr + 16 * i];
      v.y = tile[tc * 4 + 1][tr + 16 * i];
      v.z = tile[tc * 4 + 2][tr + 16 * i];
      v.w = tile[tc * 4 + 3][tr + 16 * i];
      *(ushort4*)(db + (size_t)c * NN + m0 + tc * 4) = v;
    }
  }
}

// ---------------- MFMA GEMM, 128x128 tile, BK=64, single-barrier dbuf pipeline (R4-proven) ----------------
// DECA: A decoded from mask1 (convention P, k over e). DECB: B decoded from mask2 (canonical, k over n).
// Decode = zero-fill + sparse scatter of 1.0bf16. z = zr*SK + kz. C at P + kz*c_ps + zr*c_rs.
// Optional f32 epilogue col-scale cscale[zr*cs_rs+col].
template <int DECA, int DECB>
__global__ __launch_bounds__(256) void k_gemm3(
    const unsigned short* __restrict__ A, const unsigned short* __restrict__ BT,
    int K, int SK, int lda, int ldb, long a_rs, long b_rs,
    unsigned short* __restrict__ P, long c_ps, long c_rs, int ldc,
    const unsigned long long* __restrict__ dm, int dnw, long drow_rs,
    const float* __restrict__ cscale, long cs_rs) {
  __shared__ unsigned short Al[2][128 * 64];
  __shared__ unsigned short Bl[2][128 * 64];
  int tid = threadIdx.x, wid = tid >> 6, lane = tid & 63;
  int m0 = blockIdx.x << 7, n0 = blockIdx.y << 7;
  int z = blockIdx.z, zr = z / SK, kz = z - zr * SK;
  int Kc = K / SK;
  int r8 = lane >> 3, c8 = lane & 7;
  int swz = ((c8 ^ r8) << 3);
  const unsigned short* Ab = A + (DECA ? 0 : ((size_t)zr * a_rs + (size_t)m0 * lda + (size_t)kz * Kc));
  const unsigned short* Bb = BT + (DECB ? 0 : ((size_t)zr * b_rs + (size_t)n0 * ldb + (size_t)kz * Kc));
  const unsigned int* mrow = nullptr;
  int drow = 0, dhalf = 0, dsw = 0;
  if (DECA || DECB) {
    drow = tid >> 1; dhalf = tid & 1;
    long mrowOff = (long)zr * drow_rs + (DECA ? m0 : n0) + drow;
    mrow = (const unsigned int*)(dm + (size_t)mrowOff * dnw);
    dsw = drow & 7;
  }
  auto stage = [&](int pb, int k0) {
    if (!DECA) {
#pragma unroll
      for (int t = 0; t < 4; t++) {
        int rbase = (wid << 5) + (t << 3);
        int row = rbase + r8;
        async16(Ab + (size_t)row * lda + k0 + swz, &Al[pb][rbase * 64 + lane * 8]);
      }
    }
    if (!DECB) {
#pragma unroll
      for (int t = 0; t < 4; t++) {
        int rbase = (wid << 5) + (t << 3);
        int row = rbase + r8;
        async16(Bb + (size_t)row * ldb + k0 + swz, &Bl[pb][rbase * 64 + lane * 8]);
      }
    }
    if (DECA || DECB) {
      unsigned short* Dl = DECA ? &Al[pb][0] : &Bl[pb][0];
      long kglob = (long)kz * Kc + k0;
      uint4 zz = {0u, 0u, 0u, 0u};
#pragma unroll
      for (int g = 0; g < 4; g++) {
        int chunk = ((dhalf << 2) | g) ^ dsw;
        *(uint4*)&Dl[drow * 64 + chunk * 8] = zz;
      }
      if (DECA) {
        // convention P: e = jj*256 + l*4 + c; this thread covers kl in [dhalf*32, dhalf*32+32)
        int jj = (int)(kglob >> 8);
        int lbase = (((int)kglob & 255) >> 2) + (dhalf << 3);  // multiple of 8
        int u32sel = lbase >> 5, sh = lbase & 31;
#pragma unroll
        for (int c = 0; c < 4; c++) {
          unsigned int wbits = mrow[(((jj << 2) + c) << 1) + u32sel];
          unsigned int bb = (wbits >> sh) & 0xffu;
          while (bb) {
            int b = __builtin_ctz(bb);
            bb &= bb - 1;
            int kl = (((dhalf << 3) + b) << 2) | c;
            Dl[drow * 64 + (((kl >> 3) ^ dsw) << 3) + (kl & 7)] = (unsigned short)0x3F80;
          }
        }
      } else {
        unsigned int bits = mrow[(kglob >> 5) + dhalf];
        while (bits) {
          int b = __builtin_ctz(bits);
          bits &= bits - 1;
          int kl = (dhalf << 5) + b;
          Dl[drow * 64 + (((kl >> 3) ^ dsw) << 3) + (kl & 7)] = (unsigned short)0x3F80;
        }
      }
    }
  };
  int wm = (wid >> 1) << 6, wn = (wid & 1) << 6;
  int fm = lane & 15, quad = lane >> 4;
  int f7 = fm & 7;
  floatx4 acc[4][4];
#pragma unroll
  for (int i = 0; i < 4; i++)
#pragma unroll
    for (int j = 0; j < 4; j++) acc[i][j] = (floatx4){0.f, 0.f, 0.f, 0.f};
  auto compute = [&](int pb) {
#pragma unroll
    for (int ks = 0; ks < 2; ks++) {
      int kg = (ks << 2) | quad;
      int ko = ((kg ^ f7) << 3);
      bf16x8 a[4], b[4];
#pragma unroll
      for (int i = 0; i < 4; i++) {
        a[i] = *(const bf16x8*)&Al[pb][(wm + i * 16 + fm) * 64 + ko];
        b[i] = *(const bf16x8*)&Bl[pb][(wn + i * 16 + fm) * 64 + ko];
      }
#pragma unroll
      for (int i = 0; i < 4; i++)
#pragma unroll
        for (int j = 0; j < 4; j++)
          acc[i][j] = __builtin_amdgcn_mfma_f32_16x16x32_bf16(a[i], b[j], acc[i][j], 0, 0, 0);
    }
  };
  stage(0, 0);
  __syncthreads();
  for (int k0 = 0; k0 < Kc; k0 += 128) {   // all callers have Kc % 128 == 0
    if (k0 + 64 < Kc) stage(1, k0 + 64);
    compute(0);
    __syncthreads();
    if (k0 + 128 < Kc) stage(0, k0 + 128);
    compute(1);
    __syncthreads();
  }
  unsigned short* Cb = P + (size_t)kz * c_ps + (size_t)zr * c_rs;
  float csc[4];
#pragma unroll
  for (int ni = 0; ni < 4; ni++)
    csc[ni] = cscale ? cscale[(size_t)zr * cs_rs + n0 + wn + ni * 16 + fm] : 1.0f;
#pragma unroll
  for (int mi = 0; mi < 4; mi++)
#pragma unroll
    for (int ni = 0; ni < 4; ni++)
#pragma unroll
      for (int v = 0; v < 4; v++) {
        int row = m0 + wm + mi * 16 + quad * 4 + v;
        int col = n0 + wn + ni * 16 + fm;
        Cb[(size_t)row * ldc + col] = f2b(acc[mi][ni][v] * csc[ni]);
      }
}

// ---- reduce SK bf16 partials per zr(=r) -> bf16 out[zr][region], scaled by de^-2 over e=i%EE ----
__global__ void k_red_b(const unsigned short* __restrict__ P, unsigned short* __restrict__ out,
                        int SK, long region, const float* __restrict__ de,
                        const float* __restrict__ rel, float* __restrict__ cszero) {
  if (cszero && blockIdx.x == 0 && blockIdx.y == 0) {
    cszero[threadIdx.x] = 0.f;
    cszero[threadIdx.x + 256] = 0.f;
  }
  long i = ((long)blockIdx.x * 256 + threadIdx.x) * 8;
  int zr = blockIdx.y;
  const unsigned short* p = P + (size_t)zr * SK * region + i;
  float s[8] = {0, 0, 0, 0, 0, 0, 0, 0};
  for (int k = 0; k < SK; k++) {
    const unsigned short* q = p + (size_t)k * region;
    ushort4 a = *(const ushort4*)q;
    ushort4 b = *(const ushort4*)(q + 4);
    s[0] += b2f(a.x); s[1] += b2f(a.y); s[2] += b2f(a.z); s[3] += b2f(a.w);
    s[4] += b2f(b.x); s[5] += b2f(b.y); s[6] += b2f(b.z); s[7] += b2f(b.w);
  }
  float rwr = rel_w(rel, zr);
  int e0 = (int)(i & (EE - 1));
  float scl[8];
#pragma unroll
  for (int j = 0; j < 8; j++) scl[j] = 1.0f / (rwr * de[zr * EE + e0 + j] + 1e-8f);
  ushort4 o0, o1;
  o0.x = f2b(s[0] * scl[0]); o0.y = f2b(s[1] * scl[1]); o0.z = f2b(s[2] * scl[2]); o0.w = f2b(s[3] * scl[3]);
  o1.x = f2b(s[4] * scl[4]); o1.y = f2b(s[5] * scl[5]); o1.z = f2b(s[6] * scl[6]); o1.w = f2b(s[7] * scl[7]);
  unsigned short* d = out + (size_t)zr * region + i;
  *(ushort4*)d = o0;
  *(ushort4*)(d + 4) = o1;
}

// ---- reduce SK bf16 partials per r of [NN][FF] -> Hcat[n][r*FF+f] bf16, row-scaled by dvs ----
__global__ void k_red_hcatb(const unsigned short* __restrict__ P, unsigned short* __restrict__ out,
                            int SK, const float* __restrict__ dvs) {
  long i = ((long)blockIdx.x * 256 + threadIdx.x) * 8;
  int r = blockIdx.y;
  const unsigned short* p = P + (size_t)r * SK * (NN * FF) + i;
  float s[8] = {0, 0, 0, 0, 0, 0, 0, 0};
  for (int k = 0; k < SK; k++) {
    const unsigned short* q = p + (size_t)k * (NN * FF);
    ushort4 a = *(const ushort4*)q;
    ushort4 b = *(const ushort4*)(q + 4);
    s[0] += b2f(a.x); s[1] += b2f(a.y); s[2] += b2f(a.z); s[3] += b2f(a.w);
    s[4] += b2f(b.x); s[5] += b2f(b.y); s[6] += b2f(b.z); s[7] += b2f(b.w);
  }
  long n = i >> 7;
  int f = (int)(i & 127);
  float dv = dvs[(size_t)r * NN + n];
  ushort4 o0, o1;
  o0.x = f2b(s[0] * dv); o0.y = f2b(s[1] * dv); o0.z = f2b(s[2] * dv); o0.w = f2b(s[3] * dv);
  o1.x = f2b(s[4] * dv); o1.y = f2b(s[5] * dv); o1.z = f2b(s[6] * dv); o1.w = f2b(s[7] * dv);
  unsigned short* d = out + n * (RR * FF) + r * FF + f;
  *(ushort4*)d = o0;
  *(ushort4*)(d + 4) = o1;
}

// ---- reduce Z bf16 partials of [NN][HDD] -> convout f32 + fused BN stats; per-slot row scale ----
__global__ void k_redstats(const unsigned short* __restrict__ P, float* __restrict__ out,
                           float* __restrict__ cs, float* __restrict__ cs2, int Z,
                           const float* __restrict__ rs, int rshift) {
  __shared__ float sm[2][8][256];
  int cg = (threadIdx.x & 31) << 3;
  int rowt = threadIdx.x >> 5;
  int r0 = blockIdx.x * 32;
  float s[8] = {0, 0, 0, 0, 0, 0, 0, 0}, s2[8] = {0, 0, 0, 0, 0, 0, 0, 0};
  for (int j = 0; j < 4; j++) {
    int row = r0 + rowt * 4 + j;
    long idx = (long)row * HDD + cg;
    float acc[8] = {0, 0, 0, 0, 0, 0, 0, 0};
    for (int z = 0; z < Z; z++) {
      const unsigned short* p = P + (size_t)z * ((long)NN * HDD) + idx;
      float w_ = rs ? rs[(size_t)(z >> rshift) * NN + row] : 1.0f;
      ushort4 a = *(const ushort4*)p;
      ushort4 b = *(const ushort4*)(p + 4);
      acc[0] += b2f(a.x) * w_; acc[1] += b2f(a.y) * w_; acc[2] += b2f(a.z) * w_; acc[3] += b2f(a.w) * w_;
      acc[4] += b2f(b.x) * w_; acc[5] += b2f(b.y) * w_; acc[6] += b2f(b.z) * w_; acc[7] += b2f(b.w) * w_;
    }
    float4 o0 = {acc[0], acc[1], acc[2], acc[3]};
    float4 o1 = {acc[4], acc[5], acc[6], acc[7]};
    *(float4*)(out + idx) = o0;
    *(float4*)(out + idx + 4) = o1;
#pragma unroll
    for (int i = 0; i < 8; i++) { s[i] += acc[i]; s2[i] += acc[i] * acc[i]; }
  }
#pragma unroll
  for (int i = 0; i < 8; i++) { sm[0][rowt][cg + i] = s[i]; sm[1][rowt][cg + i] = s2[i]; }
  __syncthreads();
  int c = threadIdx.x;
  float a0 = 0, a1 = 0;
#pragma unroll
  for (int t = 0; t < 8; t++) { a0 += sm[0][t][c]; a1 += sm[1][t][c]; }
  atomicAdd(&cs[c], a0);
  atomicAdd(&cs2[c], a1);
}

// ---- final: d_out = X + b3 + sum_Z dv-scaled bf16 partials [Z][NN][FF] ----
__global__ void k_red_out(const unsigned short* __restrict__ P, const float* __restrict__ X,
                          const float* __restrict__ b3, float* __restrict__ out, int Z,
                          const float* __restrict__ rs, int rshift) {
  long i = ((long)blockIdx.x * 256 + threadIdx.x) * 4;
  long n = i >> 7;
  int f = (int)(i & 127);
  float4 s = *(const float4*)(X + i);
  s.x += b3[f]; s.y += b3[f + 1]; s.z += b3[f + 2]; s.w += b3[f + 3];
  for (int z = 0; z < Z; z++) {
    float w_ = rs[(size_t)(z >> rshift) * NN + n];
    ushort4 v = *(const ushort4*)(P + (size_t)z * (NN * FF) + i);
    s.x += b2f(v.x) * w_; s.y += b2f(v.y) * w_; s.z += b2f(v.z) * w_; s.w += b2f(v.w) * w_;
  }
  *(float4*)(out + i) = s;
}

// ---- BN (batch stats) -> LN -> ELU -> bf16 [NN][HDD] ----
__global__ void k_bnlnelu(const float* __restrict__ x, const float* __restrict__ cs, const float* __restrict__ cs2,
                          const float* __restrict__ bg, const float* __restrict__ bb,
                          const float* __restrict__ lg, const float* __restrict__ lb,
                          unsigned short* __restrict__ out) {
  int wid = threadIdx.x >> 6, lane = threadIdx.x & 63;
  int n = blockIdx.x * 4 + wid;
  float y[4];
  float m = 0.f;
#pragma unroll
  for (int j = 0; j < 4; j++) {
    int c = lane + 64 * j;
    float mu = cs[c] * (1.0f / NN);
    float var = cs2[c] * (1.0f / NN) - mu * mu;
    float xv = x[(size_t)n * HDD + c];
    y[j] = (xv - mu) * rsqrtf(var + 1e-5f) * bg[c] + bb[c];
    m += y[j];
  }
  for (int off = 32; off; off >>= 1) m += __shfl_down(m, off);
  m = __shfl(m, 0) * (1.0f / HDD);
  float var = 0.f;
#pragma unroll
  for (int j = 0; j < 4; j++) { float d = y[j] - m; var += d * d; }
  for (int off = 32; off; off >>= 1) var += __shfl_down(var, off);
  var = __shfl(var, 0) * (1.0f / HDD);
  float inv = rsqrtf(var + 1e-5f);
#pragma unroll
  for (int j = 0; j < 4; j++) {
    int c = lane + 64 * j;
    float z = (y[j] - m) * inv * lg[c] + lb[c];
    z = z > 0.f ? z : expm1f(z);
    out[(size_t)n * HDD + c] = f2b(z);
  }
}

extern "C" void kernel_launch(void* const* d_in, const int* in_sizes, int n_in,
                              void* d_out, int out_size, void* d_ws, size_t ws_size,
                              hipStream_t stream) {
  const float* X   = (const float*)d_in[0];
  const float* H   = (const float*)d_in[1];
  const float* W1  = (const float*)d_in[2];
  const float* W2  = (const float*)d_in[3];
  const float* W3  = (const float*)d_in[4];
  const float* imp = (const float*)d_in[5];
  const float* b3  = (const float*)d_in[8];
  const float* bng = (const float*)d_in[9];
  const float* bnb = (const float*)d_in[10];
  const float* lng = (const float*)d_in[11];
  const float* lnb = (const float*)d_in[12];
  const float* rel = (const float*)d_in[13];
  (void)in_sizes; (void)n_in; (void)out_size; (void)ws_size;

  char* w = (char*)d_ws;
  size_t off = 0;
  auto alloc = [&](size_t bytes) -> void* {
    void* p = w + off;
    off += (bytes + 255) & ~(size_t)255;
    return p;
  };
  float* dvs  = (float*)alloc((size_t)RR * NN * 4);
  float* de   = (float*)alloc((size_t)RR * EE * 4);
  float* cs   = (float*)alloc(2 * HDD * 4);
  unsigned long long* mask1 = (unsigned long long*)alloc((size_t)RR * NN * 32 * 8);  // 4MB
  unsigned long long* mask2 = (unsigned long long*)alloc((size_t)RR * EE * 64 * 8);  // 4MB
  unsigned short* bufP = (unsigned short*)alloc((size_t)16 * NN * HDD * 2);    // 32MB bf16 partials
  unsigned short* bufC = (unsigned short*)alloc((size_t)RR * EE * HDD * 2);    // 4MB
  unsigned short* bufD = (unsigned short*)alloc((size_t)RR * EE * HDD * 2);    // 4MB
  unsigned short* bufE = (unsigned short*)alloc((size_t)RR * EE * HDD * 2);    // 4MB
  float* convout = (float*)alloc((size_t)NN * HDD * 4);                        // 4MB
  unsigned short* Xb    = (unsigned short*)alloc((size_t)NN * HDD * 2);        // 2MB
  unsigned short* XdvT  = (unsigned short*)alloc((size_t)RR * FF * NN * 2);    // 4MB (later: ydvT)
  unsigned short* hwdvT = (unsigned short*)alloc((size_t)RR * HDD * NN * 2);   // 8MB
  unsigned short* W1catT = (unsigned short*)alloc((size_t)RR * FF * HDD * 2);
  unsigned short* W2T    = (unsigned short*)alloc((size_t)RR * HDD * HDD * 2);
  unsigned short* W3T    = (unsigned short*)alloc((size_t)RR * HDD * FF * 2);

  // ---- prep (2 dispatches) ----
  k_prep1<<<4096 + 2048 + 34, 256, 0, stream>>>(H, rel, W1, W2, W3, imp,
                                                dvs, mask1, W1catT, W2T, W3T, de, cs);
  k_prep2<<<256 + 512, 256, 0, stream>>>(mask1, mask2, de, X, dvs, XdvT);

  // ---- layer 1 (128 -> 256) ----
  // G1: raw1T[r][f][e] = sum_n XdvT[r][f][n] B2[r,e,n]   M=128,N=2048,K=4096, z=(r,SK8)
  k_gemm3<0, 1><<<dim3(1, EE / 128, RR * 8), 256, 0, stream>>>(
      XdvT, nullptr, NN, 8, NN, 0, (long)FF * NN, 0,
      bufP, (long)FF * EE, 8L * FF * EE, EE, mask2, NN / 64, EE, nullptr, 0);
  k_red_b<<<dim3((FF * EE) / 2048, RR), 256, 0, stream>>>(
      bufP, bufC, 8, (long)FF * EE, de, rel, nullptr);  // bufC = de^2 * raw1T
  // G2: Hcat_raw[n][f] = sum_e B1[r,n,e] bufC[r][f][e]   M=4096,N=128,K=2048, z=(r,SK4)  [bumped]
  k_gemm3<1, 0><<<dim3(NN / 128, 1, RR * 4), 256, 0, stream>>>(
      nullptr, bufC, EE, 4, 0, EE, 0, (long)FF * EE,
      bufP, (long)NN * FF, 4L * NN * FF, FF, mask1, EE / 64, NN, nullptr, 0);
  k_red_hcatb<<<dim3((NN * FF) / 2048, RR), 256, 0, stream>>>(bufP, bufD, 4, dvs);  // Hcatb [4096][512]
  // G3: convout = Hcatb @ W1cat   M=4096,N=256,K=512, SK=4 (b1 dropped: BN-invariant)
  k_gemm3<0, 0><<<dim3(NN / 128, HDD / 128, 4), 256, 0, stream>>>(
      bufD, W1catT, RR * FF, 4, RR * FF, RR * FF, 0, 0,
      bufP, (long)NN * HDD, 0, HDD, nullptr, 0, 0, nullptr, 0);
  k_redstats<<<NN / 32, 256, 0, stream>>>(bufP, convout, cs, cs + HDD, 4, nullptr, 0);
  k_bnlnelu<<<NN / 4, 256, 0, stream>>>(convout, cs, cs + HDD, bng, bnb, lng, lnb, Xb);

  // ---- layer 2 (256 -> 256), W2 applied FIRST (commutes with diag e-scales) ----
  // hwdvT[r][o][n] = dv[r,n] * sum_c W2T[r,o,c] Xb[n,c]   M=256,N=4096,K=256, z=r
  k_gemm3<0, 0><<<dim3(HDD / 128, NN / 128, RR), 256, 0, stream>>>(
      W2T, Xb, HDD, 1, HDD, HDD, (long)HDD * HDD, 0,
      hwdvT, 0, (long)HDD * NN, NN, nullptr, 0, 0, dvs, NN);
  // L2-1: raw2[r][o][e] = sum_n hwdvT[r][o][n] B2[r,e,n]   M=256,N=2048,K=4096, z=(r,SK4)
  k_gemm3<0, 1><<<dim3(HDD / 128, EE / 128, RR * 4), 256, 0, stream>>>(
      hwdvT, nullptr, NN, 4, NN, 0, (long)HDD * NN, 0,
      bufP, (long)HDD * EE, 4L * HDD * EE, EE, mask2, NN / 64, EE, nullptr, 0);
  k_red_b<<<dim3((HDD * EE) / 2048, RR), 256, 0, stream>>>(
      bufP, bufE, 4, (long)HDD * EE, de, rel, cs);  // bufE = de^2 * raw2; zeroes cs for L2 stats
  // L2-3: raw_out[n][o] = sum_e B1[r,n,e] bufE[r][o][e]   M=4096,N=256,K=2048, z=(r,SK2)
  k_gemm3<1, 0><<<dim3(NN / 128, HDD / 128, RR * 2), 256, 0, stream>>>(
      nullptr, bufE, EE, 2, 0, EE, 0, (long)HDD * EE,
      bufP, (long)NN * HDD, 2L * NN * HDD, HDD, mask1, EE / 64, NN, nullptr, 0);
  k_redstats<<<NN / 32, 256, 0, stream>>>(bufP, convout, cs, cs + HDD, 8, dvs, 1);
  k_bnlnelu<<<NN / 4, 256, 0, stream>>>(convout, cs, cs + HDD, bng + HDD, bnb + HDD, lng + HDD, lnb + HDD, Xb);

  // ---- layer 3 (256 -> 128), W3 applied first ----
  // ydvT[r][f][n] = (sum_c W3T[r,f,c] Xb[n,c]) * dv[r,n]   M=128,N=4096,K=256, z=r
  k_gemm3<0, 0><<<dim3(1, NN / 128, RR), 256, 0, stream>>>(
      W3T, Xb, HDD, 1, HDD, HDD, (long)FF * HDD, 0,
      XdvT, 0, (long)FF * NN, NN, nullptr, 0, 0, dvs, NN);
  // L3-1: raw3[r][f][e] = sum_n ydvT[r][f][n] B2[r,e,n]   M=128,N=2048,K=4096, z=(r,SK8)
  k_gemm3<0, 1><<<dim3(1, EE / 128, RR * 8), 256, 0, stream>>>(
      XdvT, nullptr, NN, 8, NN, 0, (long)FF * NN, 0,
      bufP, (long)FF * EE, 8L * FF * EE, EE, mask2, NN / 64, EE, nullptr, 0);
  k_red_b<<<dim3((FF * EE) / 2048, RR), 256, 0, stream>>>(
      bufP, bufC, 8, (long)FF * EE, de, rel, nullptr);  // bufC = de^2 * raw3
  // L3-3: P[z] = B1[r] @ bufC[r]   M=4096,N=128,K=2048, z=(r,SK4)  [bumped]
  k_gemm3<1, 0><<<dim3(NN / 128, 1, RR * 4), 256, 0, stream>>>(
      nullptr, bufC, EE, 4, 0, EE, 0, (long)FF * EE,
      bufP, (long)NN * FF, 4L * NN * FF, FF, mask1, EE / 64, NN, nullptr, 0);
  // d_out = X + b3 + sum_z dv[r][n] * P[z]
  k_red_out<<<(NN * FF) / 1024, 256, 0, stream>>>(bufP, X, b3, (float*)d_out, 16, dvs, 2);
}